// Round 5
// baseline (308.746 us; speedup 1.0000x reference)
//
#include <hip/hip_runtime.h>
#include <hip/hip_bf16.h>

#define BB 4
#define HH 160
#define WW 160
#define HWD (HH * WW)                   // 25600
#define OUT_ELEMS (BB * 64 * HWD)       // 6,553,600
#define EPSBN 1e-5f
#define CHSTRIDE (8 * HWD)              // 8-channel chunk stride
#define NSLOT 128                       // BN partial slots per channel-stat
#define NBLK 800                        // persistent grid (2 tiles/block)

typedef __attribute__((ext_vector_type(8))) short bf16x8;
typedef __attribute__((ext_vector_type(4))) float f32x4;

__device__ inline unsigned pack2bf(float a, float b) {
  __hip_bfloat162 h2 = __float22bfloat162_rn(float2{a, b});
  unsigned u;
  __builtin_memcpy(&u, &h2, 4);
  return u;
}
__device__ inline unsigned short bf16bits(float a) {
  __hip_bfloat16 h = __float2bfloat16(a);
  unsigned short u;
  __builtin_memcpy(&u, &h, 2);
  return u;
}

// ---------------------------------------------------------------------------
// prep: prepacked MFMA B-fragments (K permuted to kappa = tap*8 + ch within
// each 8-ch chunk, 96-padded; taps 9..11 zero) + zero BN partials + counter.
// ---------------------------------------------------------------------------
__global__ void prep_kernel(const float* __restrict__ cw,
                            const float* __restrict__ ow,
                            unsigned short* __restrict__ Bp,
                            unsigned short* __restrict__ B2p,
                            float* __restrict__ part,
                            int* __restrict__ cnt) {
  int i = blockIdx.x * 256 + threadIdx.x;
  if (i == 0) *cnt = 0;
  if (i < 16384) part[i] = 0.f;
  if (i < 49152) {                      // dconv weights conv_w[n][c][t], nt 0..3
    int j = i & 7, l = (i >> 3) & 63, rest = i >> 9;
    int ki = rest % 24, nt = rest / 24;
    int kp = ki * 32 + ((l >> 4) << 3) + j;
    int chunk = kp / 96, kq = kp % 96;
    int t = kq >> 3, c = kq & 7;
    int n = nt * 16 + (l & 15);
    float v = (t < 9) ? cw[n * 576 + (chunk * 8 + c) * 9 + t] : 0.f;
    Bp[i] = bf16bits(v);
  }
  if (i < 24576) {                      // offconv weights, nt 0..1, n<18
    int j = i & 7, l = (i >> 3) & 63, rest = i >> 9;
    int ki = rest % 24, nt = rest / 24;
    int kp = ki * 32 + ((l >> 4) << 3) + j;
    int chunk = kp / 96, kq = kp % 96;
    int t = kq >> 3, c = kq & 7;
    int n = nt * 16 + (l & 15);
    float v = (t < 9 && n < 18) ? ow[n * 576 + (chunk * 8 + c) * 9 + t] : 0.f;
    B2p[i] = bf16bits(v);
  }
}

// ---------------------------------------------------------------------------
// PERSISTENT fused offconv + dconv + BN + ReLU (round-1 tile pipeline x2).
// Grid 800, block k (XCD k%8) owns tiles t = (k&7)*200 + (k>>3) + j*100,
// j=0,1 -- two halves of its XCD's 80-row band, so halo re-reads stay in one
// 4MB L2. After both tiles: device-wide spin barrier (capacity-safe: LDS
// 26112B -> 6 blk/CU, launch_bounds caps VGPR at 128 -> >=4 blk/CU => 1024
// resident slots >= 800 blocks), then BN stats from f32 partials (f64
// accumulate) and BN+ReLU applied: tile-2 from live acc registers (single
// store, never written unnormalized), tile-1 via L2-resident re-read.
// Replaces reduce_kernel + bnapply_kernel + 2 launch gaps + 52MB HBM trip.
// ---------------------------------------------------------------------------
__global__ __launch_bounds__(256, 4) void persist_kernel(
    const float* __restrict__ x, const float* __restrict__ d,
    const bf16x8* __restrict__ Bp, const bf16x8* __restrict__ B2p,
    float* __restrict__ out, float* __restrict__ off_out,
    float* __restrict__ part, int* __restrict__ cnt,
    const float* __restrict__ gamma, const float* __restrict__ beta) {
  const int tid = threadIdx.x;
  const int wv = tid >> 6, lane = tid & 63;
  const int lo = lane >> 4, li = lane & 15;
  const int px = li, py = wv;

  __shared__ float patch[189 * 12];    // phase1: 108x12 region; phase2: full
  __shared__ bf16x8 Af[768];
  __shared__ float offs_s[64 * 18];    // per-pixel 9 taps x (dy,dx)

  f32x4 acc[4];                        // tile-2 acc survives to post-barrier
  int b = 0, ty0 = 0, tx0 = 0;         // current tile coords
  int b1 = 0, ty1 = 0, tx1 = 0;        // tile-1 coords saved for BN re-read

  for (int j = 0; j < 2; ++j) {
    __syncthreads();  // previous tile's LDS reads done before reuse
    {
      int t = (blockIdx.x & 7) * 200 + (blockIdx.x >> 3) + j * 100;
      b = t / 400;
      int rr = t % 400;
      ty0 = (rr / 10) * 4;
      tx0 = (rr % 10) * 16;
    }
    const int h = ty0 + py, w = tx0 + px;

    // ---- phase-2 x-staging addresses ----
    int goffx[6], laddrx[6];
    bool gokx[6];
#pragma unroll
    for (int i = 0; i < 6; ++i) {
      int l = tid + i * 256;
      int c = l / 189, rc = l % 189, r = rc / 21, col = rc % 21;
      int gy = ty0 - 2 + r, gx = tx0 - 2 + col;
      gokx[i] = (l < 1512) && gy >= 0 && gy < HH && gx >= 0 && gx < WW;
      goffx[i] = ((b * 64 + c) * HH + gy) * WW + gx;
      laddrx[i] = rc * 12 + c;
    }

    // ================= phase 1: offconv =================
    f32x4 po0{0.f, 0.f, 0.f, 0.f}, po1{0.f, 0.f, 0.f, 0.f};
    const int ntA = wv >> 1, mh = wv & 1;
    {
      int poff[3];
      bool tre1[3];
#pragma unroll
      for (int kk = 0; kk < 3; ++kk) {
        int t = kk * 4 + lo;
        tre1[kk] = (t < 9);
        poff[kk] = tre1[kk] ? ((py + t / 3) * 18 + px + t % 3) : 0;
      }

      int goff[4], laddr[4];
      bool gok[4];
#pragma unroll
      for (int i = 0; i < 4; ++i) {
        int l = tid + i * 256;
        int c = l / 108, rc = l % 108, r = rc / 18, col = rc % 18;
        int gy = ty0 - 1 + r, gx = tx0 - 1 + col;
        gok[i] = (l < 864) && gy >= 0 && gy < HH && gx >= 0 && gx < WW;
        goff[i] = ((b * 64 + c) * HH + gy) * WW + gx;
        laddr[i] = rc * 12 + c;
      }
      float g[4];
#pragma unroll
      for (int i = 0; i < 4; ++i) g[i] = gok[i] ? d[goff[i]] : 0.f;

      for (int chunk = 0; chunk < 8; ++chunk) {
        bf16x8 bw0 = B2p[((ntA * 24 + chunk * 3 + 0) << 6) + lane];
        bf16x8 bw1 = B2p[((ntA * 24 + chunk * 3 + 1) << 6) + lane];
        bf16x8 bw2 = B2p[((ntA * 24 + chunk * 3 + 2) << 6) + lane];
#pragma unroll
        for (int i = 0; i < 4; ++i) {
          int l = tid + i * 256;
          if (l < 864) patch[laddr[i]] = g[i];
        }
        __syncthreads();
        int nco = ((chunk < 7) ? (chunk + 1) : 7) * CHSTRIDE;
#pragma unroll
        for (int i = 0; i < 4; ++i) g[i] = gok[i] ? d[goff[i] + nco] : 0.f;
#pragma unroll
        for (int kk = 0; kk < 3; ++kk) {
          union { bf16x8 v; unsigned u[4]; } a;
          if (tre1[kk]) {
            const float* q = patch + poff[kk] * 12;
            float4 c0 = *(const float4*)(q);
            float4 c1 = *(const float4*)(q + 4);
            a.u[0] = pack2bf(c0.x, c0.y);
            a.u[1] = pack2bf(c0.z, c0.w);
            a.u[2] = pack2bf(c1.x, c1.y);
            a.u[3] = pack2bf(c1.z, c1.w);
          } else {
            a.u[0] = a.u[1] = a.u[2] = a.u[3] = 0u;
          }
          Af[((wv * 3 + kk) << 6) + lane] = a.v;
        }
        __syncthreads();
#pragma unroll
        for (int kk = 0; kk < 3; ++kk) {
          bf16x8 bw = (kk == 0) ? bw0 : (kk == 1) ? bw1 : bw2;
          po0 = __builtin_amdgcn_mfma_f32_16x16x32_bf16(
              Af[(((mh * 2) * 3 + kk) << 6) + lane], bw, po0, 0, 0, 0);
          po1 = __builtin_amdgcn_mfma_f32_16x16x32_bf16(
              Af[(((mh * 2 + 1) * 3 + kk) << 6) + lane], bw, po1, 0, 0, 0);
        }
      }
    }

    // issue the first x chunk: latency hides under phase-1 epilogue + barrier
    float gv[6];
#pragma unroll
    for (int i = 0; i < 6; ++i) gv[i] = gokx[i] ? x[goffx[i]] : 0.f;

    {  // phase-1 epilogue: clamp, write global off_out + LDS offs_s
      const int n = ntA * 16 + li;
      if (n < 18) {
#pragma unroll
        for (int f = 0; f < 2; ++f) {
          int mf = mh * 2 + f;
          f32x4 aa = f ? po1 : po0;
          float* po =
              off_out + ((b * 18 + n) * HH + ty0 + mf) * WW + tx0 + lo * 4;
          float4 v;
          v.x = fminf(1.f, fmaxf(-1.f, aa[0]));
          v.y = fminf(1.f, fmaxf(-1.f, aa[1]));
          v.z = fminf(1.f, fmaxf(-1.f, aa[2]));
          v.w = fminf(1.f, fmaxf(-1.f, aa[3]));
          *(float4*)po = v;
          int pix = mf * 16 + lo * 4;
          offs_s[(pix + 0) * 18 + n] = v.x;
          offs_s[(pix + 1) * 18 + n] = v.y;
          offs_s[(pix + 2) * 18 + n] = v.z;
          offs_s[(pix + 3) * 18 + n] = v.w;
        }
      }
    }
    __syncthreads();

    // ================= phase 2: dconv =================
    int bs[3];
    float W00[3], W01[3], W10[3], W11[3];
    bool tre[3];
#pragma unroll
    for (int kk = 0; kk < 3; ++kk) {
      int t = kk * 4 + lo;
      tre[kk] = (t < 9);
      if (tre[kk]) {
        float dy = offs_s[(py * 16 + px) * 18 + 2 * t];
        float dx = offs_s[(py * 16 + px) * 18 + 2 * t + 1];
        float pyf = (float)(h - 1 + t / 3) + dy;
        float pxf = (float)(w - 1 + t % 3) + dx;
        float y0 = floorf(pyf), x0 = floorf(pxf);
        float wy = pyf - y0, wx = pxf - x0;
        bs[kk] = ((int)y0 - (ty0 - 2)) * 21 + ((int)x0 - (tx0 - 2));
        W00[kk] = (1.f - wy) * (1.f - wx);
        W01[kk] = (1.f - wy) * wx;
        W10[kk] = wy * (1.f - wx);
        W11[kk] = wy * wx;
      } else {
        bs[kk] = 0;
        W00[kk] = W01[kk] = W10[kk] = W11[kk] = 0.f;
      }
    }

#pragma unroll
    for (int i = 0; i < 4; ++i) acc[i] = f32x4{0.f, 0.f, 0.f, 0.f};
    const int nt = wv;

    for (int chunk = 0; chunk < 8; ++chunk) {
      bf16x8 bw0 = Bp[((nt * 24 + chunk * 3 + 0) << 6) + lane];
      bf16x8 bw1 = Bp[((nt * 24 + chunk * 3 + 1) << 6) + lane];
      bf16x8 bw2 = Bp[((nt * 24 + chunk * 3 + 2) << 6) + lane];
#pragma unroll
      for (int i = 0; i < 6; ++i) {
        int l = tid + i * 256;
        if (l < 1512) patch[laddrx[i]] = gv[i];
      }
      __syncthreads();
      int nco = ((chunk < 7) ? (chunk + 1) : 7) * CHSTRIDE;
#pragma unroll
      for (int i = 0; i < 6; ++i) gv[i] = gokx[i] ? x[goffx[i] + nco] : 0.f;
#pragma unroll
      for (int kk = 0; kk < 3; ++kk) {
        union { bf16x8 v; unsigned u[4]; } a;
        if (tre[kk]) {
          const float* q = patch + bs[kk] * 12;
          float4 p00a = *(const float4*)(q);         // corner (0,0) ch0-3
          float4 p00b = *(const float4*)(q + 4);     //            ch4-7
          float4 p01a = *(const float4*)(q + 12);    // corner (0,1)
          float4 p01b = *(const float4*)(q + 16);
          float4 p10a = *(const float4*)(q + 252);   // corner (1,0): +21*12
          float4 p10b = *(const float4*)(q + 256);
          float4 p11a = *(const float4*)(q + 264);   // corner (1,1)
          float4 p11b = *(const float4*)(q + 268);
          float w0 = W00[kk], w1 = W01[kk], w2 = W10[kk], w3 = W11[kk];
          float v0 = fmaf(w3, p11a.x, fmaf(w2, p10a.x, fmaf(w1, p01a.x, w0 * p00a.x)));
          float v1 = fmaf(w3, p11a.y, fmaf(w2, p10a.y, fmaf(w1, p01a.y, w0 * p00a.y)));
          float v2 = fmaf(w3, p11a.z, fmaf(w2, p10a.z, fmaf(w1, p01a.z, w0 * p00a.z)));
          float v3 = fmaf(w3, p11a.w, fmaf(w2, p10a.w, fmaf(w1, p01a.w, w0 * p00a.w)));
          float v4 = fmaf(w3, p11b.x, fmaf(w2, p10b.x, fmaf(w1, p01b.x, w0 * p00b.x)));
          float v5 = fmaf(w3, p11b.y, fmaf(w2, p10b.y, fmaf(w1, p01b.y, w0 * p00b.y)));
          float v6 = fmaf(w3, p11b.z, fmaf(w2, p10b.z, fmaf(w1, p01b.z, w0 * p00b.z)));
          float v7 = fmaf(w3, p11b.w, fmaf(w2, p10b.w, fmaf(w1, p01b.w, w0 * p00b.w)));
          a.u[0] = pack2bf(v0, v1);
          a.u[1] = pack2bf(v2, v3);
          a.u[2] = pack2bf(v4, v5);
          a.u[3] = pack2bf(v6, v7);
        } else {
          a.u[0] = a.u[1] = a.u[2] = a.u[3] = 0u;
        }
        Af[((wv * 3 + kk) << 6) + lane] = a.v;
      }
      __syncthreads();
#pragma unroll
      for (int kk = 0; kk < 3; ++kk) {
        bf16x8 bw = (kk == 0) ? bw0 : (kk == 1) ? bw1 : bw2;
#pragma unroll
        for (int mf = 0; mf < 4; ++mf)
          acc[mf] = __builtin_amdgcn_mfma_f32_16x16x32_bf16(
              Af[((mf * 3 + kk) << 6) + lane], bw, acc[mf], 0, 0, 0);
      }
    }

    // per-tile epilogue: BN partial sums (+ unnormalized store for tile 1)
    const int n = nt * 16 + li;
    float s = 0.f, s2 = 0.f;
#pragma unroll
    for (int mf = 0; mf < 4; ++mf) {
      if (j == 0) {
        float* po = out + ((b * 64 + n) * HH + ty0 + mf) * WW + tx0 + lo * 4;
        *(float4*)po = make_float4(acc[mf][0], acc[mf][1], acc[mf][2], acc[mf][3]);
      }
#pragma unroll
      for (int r = 0; r < 4; ++r) {
        float v = acc[mf][r];
        s += v;
        s2 = fmaf(v, v, s2);
      }
    }
    s += __shfl_xor(s, 16);  s += __shfl_xor(s, 32);
    s2 += __shfl_xor(s2, 16); s2 += __shfl_xor(s2, 32);
    if (lo == 0) {
      int slot = blockIdx.x & (NSLOT - 1);
      atomicAdd(&part[n * NSLOT + slot], s);
      atomicAdd(&part[(64 + n) * NSLOT + slot], s2);
    }
    if (j == 0) { b1 = b; ty1 = ty0; tx1 = tx0; }
  }

  // ================= device-wide barrier =================
  __syncthreads();
  if (tid == 0) {
    __threadfence();                       // partials + tile-1 stores visible
    atomicAdd(cnt, 1);
    while (atomicAdd(cnt, 0) < NBLK) __builtin_amdgcn_s_sleep(32);
  }
  __syncthreads();

  // ================= BN stats for this thread's channel =================
  const int n = wv * 16 + li;
  double s64 = 0.0, q64 = 0.0;
  {
    const float* pr = part + n * NSLOT + lo * 32;
    const float* qr = part + (64 + n) * NSLOT + lo * 32;
#pragma unroll
    for (int k = 0; k < 8; ++k) {
      float4 a4 = *(const float4*)(pr + k * 4);
      float4 c4 = *(const float4*)(qr + k * 4);
      s64 += (double)a4.x + (double)a4.y + (double)a4.z + (double)a4.w;
      q64 += (double)c4.x + (double)c4.y + (double)c4.z + (double)c4.w;
    }
  }
  s64 += __shfl_xor(s64, 16); s64 += __shfl_xor(s64, 32);
  q64 += __shfl_xor(q64, 16); q64 += __shfl_xor(q64, 32);
  const float n_inv = 1.0f / (float)(BB * HWD);
  const float mean = (float)s64 * n_inv;
  const float var = (float)q64 * n_inv - mean * mean;
  const float bninv = gamma[n] * rsqrtf(var + EPSBN);
  const float bnbt = beta[n];

  // tile-2: BN+ReLU straight from live registers (single store)
#pragma unroll
  for (int mf = 0; mf < 4; ++mf) {
    float4 v;
    v.x = fmaxf(0.f, (acc[mf][0] - mean) * bninv + bnbt);
    v.y = fmaxf(0.f, (acc[mf][1] - mean) * bninv + bnbt);
    v.z = fmaxf(0.f, (acc[mf][2] - mean) * bninv + bnbt);
    v.w = fmaxf(0.f, (acc[mf][3] - mean) * bninv + bnbt);
    *(float4*)(out + ((b * 64 + n) * HH + ty0 + mf) * WW + tx0 + lo * 4) = v;
  }
  // tile-1: re-read own stores (L2-resident), BN+ReLU, store back
#pragma unroll
  for (int mf = 0; mf < 4; ++mf) {
    float* po = out + ((b1 * 64 + n) * HH + ty1 + mf) * WW + tx1 + lo * 4;
    float4 v = *(float4*)po;
    v.x = fmaxf(0.f, (v.x - mean) * bninv + bnbt);
    v.y = fmaxf(0.f, (v.y - mean) * bninv + bnbt);
    v.z = fmaxf(0.f, (v.z - mean) * bninv + bnbt);
    v.w = fmaxf(0.f, (v.w - mean) * bninv + bnbt);
    *(float4*)po = v;
  }
}

extern "C" void kernel_launch(void* const* d_in, const int* in_sizes, int n_in,
                              void* d_out, int out_size, void* d_ws, size_t ws_size,
                              hipStream_t stream) {
  const float* x = (const float*)d_in[0];
  const float* d = (const float*)d_in[1];
  const float* ow = (const float*)d_in[2];
  const float* cw = (const float*)d_in[3];
  const float* gamma = (const float*)d_in[4];
  const float* beta = (const float*)d_in[5];

  float* out = (float*)d_out;
  float* off_out = out + OUT_ELEMS;

  // ws: pad 1024 | Bp ush[49152] | B2p ush[24576] | part f32[16384] | cnt
  unsigned short* Bp = (unsigned short*)((char*)d_ws + 1024);
  unsigned short* B2p = Bp + 49152;
  float* part = (float*)(B2p + 24576);
  int* cnt = (int*)(part + 16384);

  prep_kernel<<<192, 256, 0, stream>>>(cw, ow, Bp, B2p, part, cnt);

  persist_kernel<<<NBLK, 256, 0, stream>>>(x, d, (const bf16x8*)Bp,
                                           (const bf16x8*)B2p, out, off_out,
                                           part, cnt, gamma, beta);
}

// Round 6
// 287.510 us; speedup vs baseline: 1.0739x; 1.0739x over previous
//
#include <hip/hip_runtime.h>
#include <hip/hip_bf16.h>

#define BB 4
#define HH 160
#define WW 160
#define HWD (HH * WW)                   // 25600
#define OUT_ELEMS (BB * 64 * HWD)       // 6,553,600
#define EPSBN 1e-5f
#define CHSTRIDE (8 * HWD)              // 8-channel chunk stride
#define NSLOT 256                       // BN partial slots per channel-stat

typedef __attribute__((ext_vector_type(8))) short bf16x8;
typedef __attribute__((ext_vector_type(4))) float f32x4;

__device__ inline unsigned pack2bf(float a, float b) {
  __hip_bfloat162 h2 = __float22bfloat162_rn(float2{a, b});
  unsigned u;
  __builtin_memcpy(&u, &h2, 4);
  return u;
}
__device__ inline unsigned short bf16bits(float a) {
  __hip_bfloat16 h = __float2bfloat16(a);
  unsigned short u;
  __builtin_memcpy(&u, &h, 2);
  return u;
}

// XCD-slab tile mapping: blk%8 = XCD (HW round-robin); each XCD owns 200
// spatially-contiguous tiles (an 80-pixel-row band) so halo re-reads stay
// inside one 4MB L2.
__device__ inline void tile_map(int blk, int& b, int& ty0, int& tx0) {
  int t = (blk & 7) * 200 + (blk >> 3);
  b = t / 400;
  int r = t % 400;
  ty0 = (r / 10) * 4;
  tx0 = (r % 10) * 16;
}

// ---------------------------------------------------------------------------
// prep: prepacked MFMA B-fragments (K permuted to kappa = tap*8 + ch within
// each 8-ch chunk, 96-padded; taps 9..11 zero) + zero the BN partial slots.
// ---------------------------------------------------------------------------
__global__ void prep_kernel(const float* __restrict__ cw,
                            const float* __restrict__ ow,
                            unsigned short* __restrict__ Bp,
                            unsigned short* __restrict__ B2p,
                            float* __restrict__ part) {
  int i = blockIdx.x * 256 + threadIdx.x;
  if (i < 32768) part[i] = 0.f;
  if (i < 49152) {                      // dconv weights conv_w[n][c][t], nt 0..3
    int j = i & 7, l = (i >> 3) & 63, rest = i >> 9;
    int ki = rest % 24, nt = rest / 24;
    int kp = ki * 32 + ((l >> 4) << 3) + j;
    int chunk = kp / 96, kq = kp % 96;
    int t = kq >> 3, c = kq & 7;
    int n = nt * 16 + (l & 15);
    float v = (t < 9) ? cw[n * 576 + (chunk * 8 + c) * 9 + t] : 0.f;
    Bp[i] = bf16bits(v);
  }
  if (i < 24576) {                      // offconv weights, nt 0..1, n<18
    int j = i & 7, l = (i >> 3) & 63, rest = i >> 9;
    int ki = rest % 24, nt = rest / 24;
    int kp = ki * 32 + ((l >> 4) << 3) + j;
    int chunk = kp / 96, kq = kp % 96;
    int t = kq >> 3, c = kq & 7;
    int n = nt * 16 + (l & 15);
    float v = (t < 9 && n < 18) ? ow[n * 576 + (chunk * 8 + c) * 9 + t] : 0.f;
    B2p[i] = bf16bits(v);
  }
}

// ---- phase-1 chunk body: patch write, barrier, next-chunk d + B prefetch,
//      interp -> 2 MFMAs per kk. pb is a COMPILE-TIME patch buffer index;
//      bcur/bnext are register arrays (macro keeps indexing static). ----
#define P1_CHUNK(pb, bcur, bnext, ch)                                         \
  {                                                                           \
    _Pragma("unroll") for (int i = 0; i < 4; ++i) {                           \
      int l = tid + i * 256;                                                  \
      if (l < 864) patch[pb][laddr[i]] = g[i];                                \
    }                                                                         \
    __syncthreads();                                                          \
    {                                                                         \
      int ncc = ((ch) < 7) ? (ch) + 1 : 7;                                    \
      int nco = ncc * CHSTRIDE;                                               \
      _Pragma("unroll") for (int i = 0; i < 4; ++i)                           \
          g[i] = gok[i] ? d[goff[i] + nco] : 0.f;                             \
    }                                                                         \
    if ((ch) < 7) {                                                           \
      int c3 = ((ch) + 1) * 3;                                                \
      _Pragma("unroll") for (int qq = 0; qq < 6; ++qq)                        \
          bnext[qq] = B2p[(((qq / 3) * 24 + c3 + (qq % 3)) << 6) + lane];     \
    }                                                                         \
    _Pragma("unroll") for (int kk = 0; kk < 3; ++kk) {                        \
      union { bf16x8 v; unsigned u[4]; } a;                                   \
      if (tre1[kk]) {                                                         \
        const float* qp = patch[pb] + poff[kk] * 12;                          \
        float4 c0 = *(const float4*)(qp);                                     \
        float4 c1 = *(const float4*)(qp + 4);                                 \
        a.u[0] = pack2bf(c0.x, c0.y);                                         \
        a.u[1] = pack2bf(c0.z, c0.w);                                         \
        a.u[2] = pack2bf(c1.x, c1.y);                                         \
        a.u[3] = pack2bf(c1.z, c1.w);                                         \
      } else {                                                                \
        a.u[0] = a.u[1] = a.u[2] = a.u[3] = 0u;                               \
      }                                                                       \
      po0 = __builtin_amdgcn_mfma_f32_16x16x32_bf16(a.v, bcur[kk], po0, 0, 0, 0); \
      po1 = __builtin_amdgcn_mfma_f32_16x16x32_bf16(a.v, bcur[3 + kk], po1, 0, 0, 0); \
    }                                                                         \
  }

// ---- phase-2 chunk body: patch write, barrier, next-chunk x + B prefetch,
//      bilinear interp -> 4 MFMAs per kk. ----
#define P2_CHUNK(pb, bcur, bnext, ch)                                         \
  {                                                                           \
    _Pragma("unroll") for (int i = 0; i < 6; ++i) {                           \
      int l = tid + i * 256;                                                  \
      if (l < 1512) patch[pb][laddrx[i]] = gv[i];                             \
    }                                                                         \
    __syncthreads();                                                          \
    {                                                                         \
      int ncc = ((ch) < 7) ? (ch) + 1 : 7;                                    \
      int nco = ncc * CHSTRIDE;                                               \
      _Pragma("unroll") for (int i = 0; i < 6; ++i)                           \
          gv[i] = gokx[i] ? x[goffx[i] + nco] : 0.f;                          \
    }                                                                         \
    if ((ch) < 7) {                                                           \
      int c3 = ((ch) + 1) * 3;                                                \
      _Pragma("unroll") for (int qq = 0; qq < 12; ++qq)                       \
          bnext[qq] = Bp[(((qq / 3) * 24 + c3 + (qq % 3)) << 6) + lane];      \
    }                                                                         \
    _Pragma("unroll") for (int kk = 0; kk < 3; ++kk) {                        \
      union { bf16x8 v; unsigned u[4]; } a;                                   \
      if (tre[kk]) {                                                          \
        const float* qp = patch[pb] + bs[kk] * 12;                            \
        float4 p00a = *(const float4*)(qp);                                   \
        float4 p00b = *(const float4*)(qp + 4);                               \
        float4 p01a = *(const float4*)(qp + 12);                              \
        float4 p01b = *(const float4*)(qp + 16);                              \
        float4 p10a = *(const float4*)(qp + 252);                             \
        float4 p10b = *(const float4*)(qp + 256);                             \
        float4 p11a = *(const float4*)(qp + 264);                             \
        float4 p11b = *(const float4*)(qp + 268);                             \
        float w0 = W00[kk], w1 = W01[kk], w2 = W10[kk], w3 = W11[kk];         \
        float v0 = fmaf(w3, p11a.x, fmaf(w2, p10a.x, fmaf(w1, p01a.x, w0 * p00a.x))); \
        float v1 = fmaf(w3, p11a.y, fmaf(w2, p10a.y, fmaf(w1, p01a.y, w0 * p00a.y))); \
        float v2 = fmaf(w3, p11a.z, fmaf(w2, p10a.z, fmaf(w1, p01a.z, w0 * p00a.z))); \
        float v3 = fmaf(w3, p11a.w, fmaf(w2, p10a.w, fmaf(w1, p01a.w, w0 * p00a.w))); \
        float v4 = fmaf(w3, p11b.x, fmaf(w2, p10b.x, fmaf(w1, p01b.x, w0 * p00b.x))); \
        float v5 = fmaf(w3, p11b.y, fmaf(w2, p10b.y, fmaf(w1, p01b.y, w0 * p00b.y))); \
        float v6 = fmaf(w3, p11b.z, fmaf(w2, p10b.z, fmaf(w1, p01b.z, w0 * p00b.z))); \
        float v7 = fmaf(w3, p11b.w, fmaf(w2, p10b.w, fmaf(w1, p01b.w, w0 * p00b.w))); \
        a.u[0] = pack2bf(v0, v1);                                             \
        a.u[1] = pack2bf(v2, v3);                                             \
        a.u[2] = pack2bf(v4, v5);                                             \
        a.u[3] = pack2bf(v6, v7);                                             \
      } else {                                                                \
        a.u[0] = a.u[1] = a.u[2] = a.u[3] = 0u;                               \
      }                                                                       \
      acc[0] = __builtin_amdgcn_mfma_f32_16x16x32_bf16(a.v, bcur[kk], acc[0], 0, 0, 0); \
      acc[1] = __builtin_amdgcn_mfma_f32_16x16x32_bf16(a.v, bcur[3 + kk], acc[1], 0, 0, 0); \
      acc[2] = __builtin_amdgcn_mfma_f32_16x16x32_bf16(a.v, bcur[6 + kk], acc[2], 0, 0, 0); \
      acc[3] = __builtin_amdgcn_mfma_f32_16x16x32_bf16(a.v, bcur[9 + kk], acc[3], 0, 0, 0); \
    }                                                                         \
  }

// ---------------------------------------------------------------------------
// FUSED offconv + dconv, M-SPLIT wave mapping, register-resident B with
// chunk-ahead ping-pong prefetch from the L2-resident packed weights.
// Wave wv owns output pixel row py=wv; a lane's interp value (pixel (wv,li),
// tap kk*4+lo, 8 ch) IS its own MFMA A-fragment -- Af LDS exchange (40% of
// round-1's LDS traffic, ~15KB/wave-chunk) is GONE; one barrier per chunk.
// amdgpu_waves_per_eu(3,3) pins the allocator at a 170-VGPR budget so the
// ~155-live peak fits WITHOUT scratch (rounds 2/3 spilled because the
// allocator chased 8-wave occupancy: VGPR_Count 64 + WRITE_SIZE +24MB).
// LDS = 2*9072 (patch dbuf) + 4608 (offs) = 22752 B -> 3 blocks/CU at
// waves_per_eu(3,3).
// ---------------------------------------------------------------------------
__global__ __launch_bounds__(256)
__attribute__((amdgpu_waves_per_eu(3, 3))) void fused_kernel(
    const float* __restrict__ x, const float* __restrict__ d,
    const bf16x8* __restrict__ Bp, const bf16x8* __restrict__ B2p,
    float* __restrict__ out, float* __restrict__ off_out,
    float* __restrict__ part) {
  int b, ty0, tx0;
  tile_map(blockIdx.x, b, ty0, tx0);
  const int tid = threadIdx.x;
  const int wv = tid >> 6, lane = tid & 63;
  const int lo = lane >> 4, li = lane & 15;
  const int px = li, py = wv;
  const int h = ty0 + py, w = tx0 + px;

  __shared__ float patch[2][189 * 12];  // dbuf; phase1 uses first 108*12
  __shared__ float offs_s[64 * 18];     // per-pixel 9 taps x (dy,dx)

  // ---- phase-2 x-staging addresses precomputed ----
  int goffx[6], laddrx[6];
  bool gokx[6];
#pragma unroll
  for (int i = 0; i < 6; ++i) {
    int l = tid + i * 256;
    int c = l / 189, rc = l % 189, r = rc / 21, col = rc % 21;
    int gy = ty0 - 2 + r, gx = tx0 - 2 + col;
    gokx[i] = (l < 1512) && gy >= 0 && gy < HH && gx >= 0 && gx < WW;
    goffx[i] = ((b * 64 + c) * HH + gy) * WW + gx;
    laddrx[i] = rc * 12 + c;
  }

  // ================= phase 1: offconv =================
  f32x4 po0{0.f, 0.f, 0.f, 0.f}, po1{0.f, 0.f, 0.f, 0.f};
  {
    int poff[3];
    bool tre1[3];
#pragma unroll
    for (int kk = 0; kk < 3; ++kk) {
      int t = kk * 4 + lo;
      tre1[kk] = (t < 9);
      poff[kk] = tre1[kk] ? ((py + t / 3) * 18 + px + t % 3) : 0;
    }

    int goff[4], laddr[4];
    bool gok[4];
#pragma unroll
    for (int i = 0; i < 4; ++i) {
      int l = tid + i * 256;
      int c = l / 108, rc = l % 108, r = rc / 18, col = rc % 18;
      int gy = ty0 - 1 + r, gx = tx0 - 1 + col;
      gok[i] = (l < 864) && gy >= 0 && gy < HH && gx >= 0 && gx < WW;
      goff[i] = ((b * 64 + c) * HH + gy) * WW + gx;
      laddr[i] = rc * 12 + c;
    }
    float g[4];
#pragma unroll
    for (int i = 0; i < 4; ++i) g[i] = gok[i] ? d[goff[i]] : 0.f;

    bf16x8 pA[6], pB[6];
#pragma unroll
    for (int qq = 0; qq < 6; ++qq)      // B for chunk 0
      pA[qq] = B2p[(((qq / 3) * 24 + (qq % 3)) << 6) + lane];

    for (int cp = 0; cp < 4; ++cp) {
      P1_CHUNK(0, pA, pB, 2 * cp);
      P1_CHUNK(1, pB, pA, 2 * cp + 1);
    }
  }

  // issue the first x chunk + first dconv B chunk: latency hides under the
  // phase-1 epilogue + inter-phase barrier + offset unpack
  float gv[6];
#pragma unroll
  for (int i = 0; i < 6; ++i) gv[i] = gokx[i] ? x[goffx[i]] : 0.f;
  bf16x8 qA[12], qB[12];
#pragma unroll
  for (int qq = 0; qq < 12; ++qq)       // B for chunk 0
    qA[qq] = Bp[(((qq / 3) * 24 + (qq % 3)) << 6) + lane];

  {  // phase-1 epilogue: clamp, write global off_out + LDS offs_s
    const int y = ty0 + wv;
#pragma unroll
    for (int nf = 0; nf < 2; ++nf) {
      int n = nf * 16 + li;
      if (n < 18) {
        f32x4 aa = nf ? po1 : po0;
        float4 v;
        v.x = fminf(1.f, fmaxf(-1.f, aa[0]));
        v.y = fminf(1.f, fmaxf(-1.f, aa[1]));
        v.z = fminf(1.f, fmaxf(-1.f, aa[2]));
        v.w = fminf(1.f, fmaxf(-1.f, aa[3]));
        *(float4*)(off_out + ((b * 18 + n) * HH + y) * WW + tx0 + lo * 4) = v;
        int pix = wv * 16 + lo * 4;
        offs_s[(pix + 0) * 18 + n] = v.x;
        offs_s[(pix + 1) * 18 + n] = v.y;
        offs_s[(pix + 2) * 18 + n] = v.z;
        offs_s[(pix + 3) * 18 + n] = v.w;
      }
    }
  }
  __syncthreads();

  // ================= phase 2: dconv =================
  int bs[3];
  float W00[3], W01[3], W10[3], W11[3];
  bool tre[3];
#pragma unroll
  for (int kk = 0; kk < 3; ++kk) {
    int t = kk * 4 + lo;
    tre[kk] = (t < 9);
    if (tre[kk]) {
      float2 dyx = *(const float2*)&offs_s[(wv * 16 + li) * 18 + 2 * t];
      float pyf = (float)(h - 1 + t / 3) + dyx.x;
      float pxf = (float)(w - 1 + t % 3) + dyx.y;
      float y0 = floorf(pyf), x0 = floorf(pxf);
      float wy = pyf - y0, wx = pxf - x0;
      bs[kk] = ((int)y0 - (ty0 - 2)) * 21 + ((int)x0 - (tx0 - 2));
      W00[kk] = (1.f - wy) * (1.f - wx);
      W01[kk] = (1.f - wy) * wx;
      W10[kk] = wy * (1.f - wx);
      W11[kk] = wy * wx;
    } else {
      bs[kk] = 0;
      W00[kk] = W01[kk] = W10[kk] = W11[kk] = 0.f;
    }
  }

  f32x4 acc[4];
#pragma unroll
  for (int i = 0; i < 4; ++i) acc[i] = f32x4{0.f, 0.f, 0.f, 0.f};

  for (int cp = 0; cp < 4; ++cp) {
    P2_CHUNK(0, qA, qB, 2 * cp);
    P2_CHUNK(1, qB, qA, 2 * cp + 1);
  }

  // epilogue: aligned float4 stores + fused BN partial sums.
  // wave wv holds row y=ty0+wv; lane (lo,li): x=tx0+lo*4+r, ch nf*16+li.
  const int y = ty0 + wv;
  float s[4], s2[4];
#pragma unroll
  for (int nf = 0; nf < 4; ++nf) {
    s[nf] = 0.f;
    s2[nf] = 0.f;
    float* pout = out + ((b * 64 + nf * 16 + li) * HH + y) * WW + tx0 + lo * 4;
    *(float4*)pout = make_float4(acc[nf][0], acc[nf][1], acc[nf][2], acc[nf][3]);
#pragma unroll
    for (int r = 0; r < 4; ++r) {
      float v = acc[nf][r];
      s[nf] += v;
      s2[nf] = fmaf(v, v, s2[nf]);
    }
  }
  // reduce across the 4 lanes (lo=0..3) holding the same channel set
#pragma unroll
  for (int nf = 0; nf < 4; ++nf) {
    s[nf] += __shfl_xor(s[nf], 16);
    s[nf] += __shfl_xor(s[nf], 32);
    s2[nf] += __shfl_xor(s2[nf], 16);
    s2[nf] += __shfl_xor(s2[nf], 32);
  }
  if (lo == 0) {
    int slot = blockIdx.x & (NSLOT - 1);
#pragma unroll
    for (int nf = 0; nf < 4; ++nf) {
      atomicAdd(&part[(nf * 16 + li) * NSLOT + slot], s[nf]);
      atomicAdd(&part[(64 + nf * 16 + li) * NSLOT + slot], s2[nf]);
    }
  }
}

// ---------------------------------------------------------------------------
// reduce BN partials: block j sums part[j][0..255] (f64) -> sums[j]
// ---------------------------------------------------------------------------
__global__ __launch_bounds__(256) void reduce_kernel(
    const float* __restrict__ part, double* __restrict__ sums) {
  const int j = blockIdx.x;
  __shared__ double sh[256];
  sh[threadIdx.x] = (double)part[j * NSLOT + threadIdx.x];
  __syncthreads();
  for (int t = 128; t > 0; t >>= 1) {
    if (threadIdx.x < t) sh[threadIdx.x] += sh[threadIdx.x + t];
    __syncthreads();
  }
  if (threadIdx.x == 0) sums[j] = sh[0];
}

// ---------------------------------------------------------------------------
// BN apply + ReLU, in place on d_out's conv region (float4 vectorized).
// ---------------------------------------------------------------------------
__global__ __launch_bounds__(256) void bnapply_kernel(
    float* __restrict__ out, const double* __restrict__ sums,
    const float* __restrict__ gamma, const float* __restrict__ beta) {
  const int i = blockIdx.x * 256 + threadIdx.x;
  if (i >= OUT_ELEMS / 4) return;
  const int o = (i / (HWD / 4)) & 63;
  const float n_inv = 1.0f / (float)(BB * HWD);
  float mean = (float)sums[o] * n_inv;
  float var = (float)sums[64 + o] * n_inv - mean * mean;
  float inv = gamma[o] * rsqrtf(var + EPSBN);
  float bt = beta[o];
  float4 v = ((float4*)out)[i];
  v.x = fmaxf(0.f, (v.x - mean) * inv + bt);
  v.y = fmaxf(0.f, (v.y - mean) * inv + bt);
  v.z = fmaxf(0.f, (v.z - mean) * inv + bt);
  v.w = fmaxf(0.f, (v.w - mean) * inv + bt);
  ((float4*)out)[i] = v;
}

extern "C" void kernel_launch(void* const* d_in, const int* in_sizes, int n_in,
                              void* d_out, int out_size, void* d_ws, size_t ws_size,
                              hipStream_t stream) {
  const float* x = (const float*)d_in[0];
  const float* d = (const float*)d_in[1];
  const float* ow = (const float*)d_in[2];
  const float* cw = (const float*)d_in[3];
  const float* gamma = (const float*)d_in[4];
  const float* beta = (const float*)d_in[5];

  float* out = (float*)d_out;
  float* off_out = out + OUT_ELEMS;

  // ws: sums double[128] | Bp ush[49152] | B2p ush[24576] | part f32[32768]
  double* sums = (double*)d_ws;
  unsigned short* Bp = (unsigned short*)((char*)d_ws + 1024);
  unsigned short* B2p = Bp + 49152;
  float* part = (float*)(B2p + 24576);

  prep_kernel<<<192, 256, 0, stream>>>(cw, ow, Bp, B2p, part);

  fused_kernel<<<1600, 256, 0, stream>>>(x, d, (const bf16x8*)Bp,
                                         (const bf16x8*)B2p, out, off_out,
                                         part);

  reduce_kernel<<<128, 256, 0, stream>>>(part, sums);
  bnapply_kernel<<<(OUT_ELEMS / 4 + 255) / 256, 256, 0, stream>>>(
      out, sums, gamma, beta);
}

// Round 7
// 200.917 us; speedup vs baseline: 1.5367x; 1.4310x over previous
//
#include <hip/hip_runtime.h>
#include <hip/hip_bf16.h>

#define BB 4
#define HH 160
#define WW 160
#define HWD (HH * WW)                   // 25600
#define OUT_ELEMS (BB * 64 * HWD)       // 6,553,600
#define OFF_ELEMS (BB * 18 * HWD)       // 1,843,200
#define EPSBN 1e-5f
#define CHSTRIDE (8 * HWD)              // 8-channel chunk stride
#define NSLOT 256                       // BN partial slots per channel-stat

typedef __attribute__((ext_vector_type(8))) short bf16x8;
typedef __attribute__((ext_vector_type(4))) float f32x4;

__device__ inline unsigned pack2bf(float a, float b) {
  __hip_bfloat162 h2 = __float22bfloat162_rn(float2{a, b});
  unsigned u;
  __builtin_memcpy(&u, &h2, 4);
  return u;
}
__device__ inline unsigned short bf16bits(float a) {
  __hip_bfloat16 h = __float2bfloat16(a);
  unsigned short u;
  __builtin_memcpy(&u, &h, 2);
  return u;
}

// XCD-slab tile mapping: blk%8 = XCD (HW round-robin); each XCD owns 200
// spatially-contiguous tiles (an 80-pixel-row band) so halo re-reads and
// the offconv->dconv handoff stay inside one 4MB L2.
__device__ inline void tile_map(int blk, int& b, int& ty0, int& tx0) {
  int t = (blk & 7) * 200 + (blk >> 3);
  b = t / 400;
  int r = t % 400;
  ty0 = (r / 10) * 4;
  tx0 = (r % 10) * 16;
}

// ---------------------------------------------------------------------------
// prep: prepacked MFMA B-fragments (K permuted to kappa = tap*8 + ch within
// each 8-ch chunk, 96-padded; taps 9..11 zero) + zero the BN partial slots.
// ---------------------------------------------------------------------------
__global__ void prep_kernel(const float* __restrict__ cw,
                            const float* __restrict__ ow,
                            unsigned short* __restrict__ Bp,
                            unsigned short* __restrict__ B2p,
                            float* __restrict__ part) {
  int i = blockIdx.x * 256 + threadIdx.x;
  if (i < 32768) part[i] = 0.f;
  if (i < 49152) {                      // dconv weights conv_w[n][c][t], nt 0..3
    int j = i & 7, l = (i >> 3) & 63, rest = i >> 9;
    int ki = rest % 24, nt = rest / 24;
    int kp = ki * 32 + ((l >> 4) << 3) + j;
    int chunk = kp / 96, kq = kp % 96;
    int t = kq >> 3, c = kq & 7;
    int n = nt * 16 + (l & 15);
    float v = (t < 9) ? cw[n * 576 + (chunk * 8 + c) * 9 + t] : 0.f;
    Bp[i] = bf16bits(v);
  }
  if (i < 24576) {                      // offconv weights, nt 0..1, n<18
    int j = i & 7, l = (i >> 3) & 63, rest = i >> 9;
    int ki = rest % 24, nt = rest / 24;
    int kp = ki * 32 + ((l >> 4) << 3) + j;
    int chunk = kp / 96, kq = kp % 96;
    int t = kq >> 3, c = kq & 7;
    int n = nt * 16 + (l & 15);
    float v = (t < 9 && n < 18) ? ow[n * 576 + (chunk * 8 + c) * 9 + t] : 0.f;
    B2p[i] = bf16bits(v);
  }
}

// ---------------------------------------------------------------------------
// FUSED offconv + dconv (round-1 verified structure: N-split waves + Af LDS
// exchange, 69.5us/64VGPR/no-spill). This round's single change: bilinear
// interp arithmetic rewritten as <4 x float> ext-vector math so the backend
// emits packed v_pk_fma_f32 / v_pk_mul_f32 (CDNA4 full-rate packed fp32):
// 40 scalar VALU ops per tap -> ~16 packed. LDS access pattern, MFMA
// schedule, register liveness all identical to round 1.
// LDS = patch 9072 + Af 12288 + offs 4608 = 25968 B -> 6 blocks/CU.
// ---------------------------------------------------------------------------
__global__ __launch_bounds__(256, 4) void fused_kernel(
    const float* __restrict__ x, const float* __restrict__ d,
    const bf16x8* __restrict__ Bp, const bf16x8* __restrict__ B2p,
    float* __restrict__ out, float* __restrict__ off_out,
    float* __restrict__ part) {
  int b, ty0, tx0;
  tile_map(blockIdx.x, b, ty0, tx0);
  const int tid = threadIdx.x;
  const int wv = tid >> 6, lane = tid & 63;
  const int lo = lane >> 4, li = lane & 15;
  const int px = li, py = wv;
  const int h = ty0 + py, w = tx0 + px;

  __shared__ float patch[189 * 12];    // phase1: 108x12 region; phase2: full
  __shared__ bf16x8 Af[768];
  __shared__ float offs_s[64 * 18];    // per-pixel 9 taps x (dy,dx)

  // ---- phase-2 x-staging addresses precomputed (held through phase 1 so
  //      the first x chunk loads can issue under the phase-1 epilogue) ----
  int goffx[6], laddrx[6];
  bool gokx[6];
#pragma unroll
  for (int i = 0; i < 6; ++i) {
    int l = tid + i * 256;
    int c = l / 189, rc = l % 189, r = rc / 21, col = rc % 21;
    int gy = ty0 - 2 + r, gx = tx0 - 2 + col;
    gokx[i] = (l < 1512) && gy >= 0 && gy < HH && gx >= 0 && gx < WW;
    goffx[i] = ((b * 64 + c) * HH + gy) * WW + gx;
    laddrx[i] = rc * 12 + c;
  }

  // ================= phase 1: offconv =================
  f32x4 acc0{0.f, 0.f, 0.f, 0.f}, acc1{0.f, 0.f, 0.f, 0.f};
  const int ntA = wv >> 1, mh = wv & 1;
  {
    int poff[3];
    bool tre[3];
#pragma unroll
    for (int kk = 0; kk < 3; ++kk) {
      int t = kk * 4 + lo;
      tre[kk] = (t < 9);
      poff[kk] = tre[kk] ? ((py + t / 3) * 18 + px + t % 3) : 0;
    }

    int goff[4], laddr[4];
    bool gok[4];
#pragma unroll
    for (int i = 0; i < 4; ++i) {
      int l = tid + i * 256;
      int c = l / 108, rc = l % 108, r = rc / 18, col = rc % 18;
      int gy = ty0 - 1 + r, gx = tx0 - 1 + col;
      gok[i] = (l < 864) && gy >= 0 && gy < HH && gx < WW && gx >= 0;
      goff[i] = ((b * 64 + c) * HH + gy) * WW + gx;
      laddr[i] = rc * 12 + c;
    }
    float g[4];
#pragma unroll
    for (int i = 0; i < 4; ++i) g[i] = gok[i] ? d[goff[i]] : 0.f;

    for (int chunk = 0; chunk < 8; ++chunk) {
      bf16x8 bw0 = B2p[((ntA * 24 + chunk * 3 + 0) << 6) + lane];
      bf16x8 bw1 = B2p[((ntA * 24 + chunk * 3 + 1) << 6) + lane];
      bf16x8 bw2 = B2p[((ntA * 24 + chunk * 3 + 2) << 6) + lane];
#pragma unroll
      for (int i = 0; i < 4; ++i) {
        int l = tid + i * 256;
        if (l < 864) patch[laddr[i]] = g[i];
      }
      __syncthreads();
      int nco = ((chunk < 7) ? (chunk + 1) : 7) * CHSTRIDE;
#pragma unroll
      for (int i = 0; i < 4; ++i) g[i] = gok[i] ? d[goff[i] + nco] : 0.f;
#pragma unroll
      for (int kk = 0; kk < 3; ++kk) {
        union { bf16x8 v; unsigned u[4]; } a;
        if (tre[kk]) {
          const float* q = patch + poff[kk] * 12;
          float4 c0 = *(const float4*)(q);
          float4 c1 = *(const float4*)(q + 4);
          a.u[0] = pack2bf(c0.x, c0.y);
          a.u[1] = pack2bf(c0.z, c0.w);
          a.u[2] = pack2bf(c1.x, c1.y);
          a.u[3] = pack2bf(c1.z, c1.w);
        } else {
          a.u[0] = a.u[1] = a.u[2] = a.u[3] = 0u;
        }
        Af[((wv * 3 + kk) << 6) + lane] = a.v;
      }
      __syncthreads();
#pragma unroll
      for (int kk = 0; kk < 3; ++kk) {
        bf16x8 bw = (kk == 0) ? bw0 : (kk == 1) ? bw1 : bw2;
        acc0 = __builtin_amdgcn_mfma_f32_16x16x32_bf16(
            Af[(((mh * 2) * 3 + kk) << 6) + lane], bw, acc0, 0, 0, 0);
        acc1 = __builtin_amdgcn_mfma_f32_16x16x32_bf16(
            Af[(((mh * 2 + 1) * 3 + kk) << 6) + lane], bw, acc1, 0, 0, 0);
      }
    }
  }

  // issue the first x chunk now: HBM latency hides under the phase-1
  // epilogue + inter-phase barrier + offset unpack
  float gv[6];
#pragma unroll
  for (int i = 0; i < 6; ++i) gv[i] = gokx[i] ? x[goffx[i]] : 0.f;

  {  // phase-1 epilogue: clamp, write global off_out + LDS offs_s
    const int n = ntA * 16 + li;
    if (n < 18) {
#pragma unroll
      for (int f = 0; f < 2; ++f) {
        int mf = mh * 2 + f;
        f32x4 a = f ? acc1 : acc0;
        float* po =
            off_out + ((b * 18 + n) * HH + ty0 + mf) * WW + tx0 + lo * 4;
        float4 v;
        v.x = fminf(1.f, fmaxf(-1.f, a[0]));
        v.y = fminf(1.f, fmaxf(-1.f, a[1]));
        v.z = fminf(1.f, fmaxf(-1.f, a[2]));
        v.w = fminf(1.f, fmaxf(-1.f, a[3]));
        *(float4*)po = v;
        int pix = mf * 16 + lo * 4;
        offs_s[(pix + 0) * 18 + n] = v.x;
        offs_s[(pix + 1) * 18 + n] = v.y;
        offs_s[(pix + 2) * 18 + n] = v.z;
        offs_s[(pix + 3) * 18 + n] = v.w;
      }
    }
  }
  __syncthreads();

  // ================= phase 2: dconv =================
  int bs[3];
  float W00[3], W01[3], W10[3], W11[3];
  bool tre[3];
#pragma unroll
  for (int kk = 0; kk < 3; ++kk) {
    int t = kk * 4 + lo;
    tre[kk] = (t < 9);
    if (tre[kk]) {
      float dy = offs_s[(py * 16 + px) * 18 + 2 * t];
      float dx = offs_s[(py * 16 + px) * 18 + 2 * t + 1];
      float pyf = (float)(h - 1 + t / 3) + dy;
      float pxf = (float)(w - 1 + t % 3) + dx;
      float y0 = floorf(pyf), x0 = floorf(pxf);
      float wy = pyf - y0, wx = pxf - x0;
      bs[kk] = ((int)y0 - (ty0 - 2)) * 21 + ((int)x0 - (tx0 - 2));
      W00[kk] = (1.f - wy) * (1.f - wx);
      W01[kk] = (1.f - wy) * wx;
      W10[kk] = wy * (1.f - wx);
      W11[kk] = wy * wx;
    } else {
      bs[kk] = 0;
      W00[kk] = W01[kk] = W10[kk] = W11[kk] = 0.f;
    }
  }

  f32x4 acc[4];
#pragma unroll
  for (int i = 0; i < 4; ++i) acc[i] = f32x4{0.f, 0.f, 0.f, 0.f};
  const int nt = wv;

  for (int chunk = 0; chunk < 8; ++chunk) {
    bf16x8 bw0 = Bp[((nt * 24 + chunk * 3 + 0) << 6) + lane];
    bf16x8 bw1 = Bp[((nt * 24 + chunk * 3 + 1) << 6) + lane];
    bf16x8 bw2 = Bp[((nt * 24 + chunk * 3 + 2) << 6) + lane];
#pragma unroll
    for (int i = 0; i < 6; ++i) {
      int l = tid + i * 256;
      if (l < 1512) patch[laddrx[i]] = gv[i];
    }
    __syncthreads();
    int nco = ((chunk < 7) ? (chunk + 1) : 7) * CHSTRIDE;
#pragma unroll
    for (int i = 0; i < 6; ++i) gv[i] = gokx[i] ? x[goffx[i] + nco] : 0.f;
#pragma unroll
    for (int kk = 0; kk < 3; ++kk) {
      union { bf16x8 v; unsigned u[4]; } a;
      if (tre[kk]) {
        const float* q = patch + bs[kk] * 12;
        // corners as ext-vector f32x4: backend emits v_pk_{mul,fma}_f32
        f32x4 p00a = *(const f32x4*)(q);           // corner (0,0) ch0-3
        f32x4 p00b = *(const f32x4*)(q + 4);       //            ch4-7
        f32x4 p01a = *(const f32x4*)(q + 12);      // corner (0,1)
        f32x4 p01b = *(const f32x4*)(q + 16);
        f32x4 p10a = *(const f32x4*)(q + 252);     // corner (1,0): +21*12
        f32x4 p10b = *(const f32x4*)(q + 256);
        f32x4 p11a = *(const f32x4*)(q + 264);     // corner (1,1)
        f32x4 p11b = *(const f32x4*)(q + 268);
        float w0 = W00[kk], w1 = W01[kk], w2 = W10[kk], w3 = W11[kk];
        f32x4 va = w0 * p00a + w1 * p01a + w2 * p10a + w3 * p11a;
        f32x4 vb = w0 * p00b + w1 * p01b + w2 * p10b + w3 * p11b;
        a.u[0] = pack2bf(va[0], va[1]);
        a.u[1] = pack2bf(va[2], va[3]);
        a.u[2] = pack2bf(vb[0], vb[1]);
        a.u[3] = pack2bf(vb[2], vb[3]);
      } else {
        a.u[0] = a.u[1] = a.u[2] = a.u[3] = 0u;
      }
      Af[((wv * 3 + kk) << 6) + lane] = a.v;
    }
    __syncthreads();
#pragma unroll
    for (int kk = 0; kk < 3; ++kk) {
      bf16x8 bw = (kk == 0) ? bw0 : (kk == 1) ? bw1 : bw2;
#pragma unroll
      for (int mf = 0; mf < 4; ++mf)
        acc[mf] = __builtin_amdgcn_mfma_f32_16x16x32_bf16(
            Af[((mf * 3 + kk) << 6) + lane], bw, acc[mf], 0, 0, 0);
    }
  }
  // epilogue: aligned float4 stores + fused BN partial sums
  const int n = nt * 16 + li;
  float s = 0.f, s2 = 0.f;
#pragma unroll
  for (int mf = 0; mf < 4; ++mf) {
    float* po = out + ((b * 64 + n) * HH + ty0 + mf) * WW + tx0 + lo * 4;
    *(float4*)po = make_float4(acc[mf][0], acc[mf][1], acc[mf][2], acc[mf][3]);
#pragma unroll
    for (int r = 0; r < 4; ++r) {
      float v = acc[mf][r];
      s += v;
      s2 = fmaf(v, v, s2);
    }
  }
  // reduce across the 4 lanes (lo=0..3) holding channel n
  s += __shfl_xor(s, 16);  s += __shfl_xor(s, 32);
  s2 += __shfl_xor(s2, 16); s2 += __shfl_xor(s2, 32);
  if (lo == 0) {
    int slot = blockIdx.x & (NSLOT - 1);
    atomicAdd(&part[n * NSLOT + slot], s);
    atomicAdd(&part[(64 + n) * NSLOT + slot], s2);
  }
}

// ---------------------------------------------------------------------------
// reduce BN partials: block j sums part[j][0..255] (f64) -> sums[j]
// ---------------------------------------------------------------------------
__global__ __launch_bounds__(256) void reduce_kernel(
    const float* __restrict__ part, double* __restrict__ sums) {
  const int j = blockIdx.x;
  __shared__ double sh[256];
  sh[threadIdx.x] = (double)part[j * NSLOT + threadIdx.x];
  __syncthreads();
  for (int t = 128; t > 0; t >>= 1) {
    if (threadIdx.x < t) sh[threadIdx.x] += sh[threadIdx.x + t];
    __syncthreads();
  }
  if (threadIdx.x == 0) sums[j] = sh[0];
}

// ---------------------------------------------------------------------------
// BN apply + ReLU, in place on d_out's conv region (float4 vectorized).
// ---------------------------------------------------------------------------
__global__ __launch_bounds__(256) void bnapply_kernel(
    float* __restrict__ out, const double* __restrict__ sums,
    const float* __restrict__ gamma, const float* __restrict__ beta) {
  const int i = blockIdx.x * 256 + threadIdx.x;
  if (i >= OUT_ELEMS / 4) return;
  const int o = (i / (HWD / 4)) & 63;
  const float n_inv = 1.0f / (float)(BB * HWD);
  float mean = (float)sums[o] * n_inv;
  float var = (float)sums[64 + o] * n_inv - mean * mean;
  float inv = gamma[o] * rsqrtf(var + EPSBN);
  float bt = beta[o];
  float4 v = ((float4*)out)[i];
  v.x = fmaxf(0.f, (v.x - mean) * inv + bt);
  v.y = fmaxf(0.f, (v.y - mean) * inv + bt);
  v.z = fmaxf(0.f, (v.z - mean) * inv + bt);
  v.w = fmaxf(0.f, (v.w - mean) * inv + bt);
  ((float4*)out)[i] = v;
}

extern "C" void kernel_launch(void* const* d_in, const int* in_sizes, int n_in,
                              void* d_out, int out_size, void* d_ws, size_t ws_size,
                              hipStream_t stream) {
  const float* x = (const float*)d_in[0];
  const float* d = (const float*)d_in[1];
  const float* ow = (const float*)d_in[2];
  const float* cw = (const float*)d_in[3];
  const float* gamma = (const float*)d_in[4];
  const float* beta = (const float*)d_in[5];

  float* out = (float*)d_out;
  float* off_out = out + OUT_ELEMS;

  // ws: sums double[128] | Bp ush[49152] | B2p ush[24576] | part f32[32768]
  double* sums = (double*)d_ws;
  unsigned short* Bp = (unsigned short*)((char*)d_ws + 1024);
  unsigned short* B2p = Bp + 49152;
  float* part = (float*)(B2p + 24576);

  prep_kernel<<<192, 256, 0, stream>>>(cw, ow, Bp, B2p, part);

  fused_kernel<<<1600, 256, 0, stream>>>(x, d, (const bf16x8*)Bp,
                                         (const bf16x8*)B2p, out, off_out,
                                         part);

  reduce_kernel<<<128, 256, 0, stream>>>(part, sums);
  bnapply_kernel<<<(OUT_ELEMS / 4 + 255) / 256, 256, 0, stream>>>(
      out, sums, gamma, beta);
}

// Round 9
// 158.440 us; speedup vs baseline: 1.9487x; 1.2681x over previous
//
#include <hip/hip_runtime.h>
#include <hip/hip_bf16.h>

#define BB 4
#define HH 160
#define WW 160
#define HWD (HH * WW)                   // 25600
#define OUT_ELEMS (BB * 64 * HWD)       // 6,553,600
#define OFF_ELEMS (BB * 18 * HWD)       // 1,843,200
#define EPSBN 1e-5f
#define CHSTRIDE (8 * HWD)              // 8-channel chunk stride
#define NSLOT 256                       // BN partial slots per channel-stat

typedef __attribute__((ext_vector_type(8))) short bf16x8;
typedef __attribute__((ext_vector_type(4))) float f32x4;

__device__ inline unsigned pack2bf(float a, float b) {
  __hip_bfloat162 h2 = __float22bfloat162_rn(float2{a, b});
  unsigned u;
  __builtin_memcpy(&u, &h2, 4);
  return u;
}
__device__ inline unsigned short bf16bits(float a) {
  __hip_bfloat16 h = __float2bfloat16(a);
  unsigned short u;
  __builtin_memcpy(&u, &h, 2);
  return u;
}

// XCD-slab tile mapping: blk%8 = XCD (HW round-robin); each XCD owns 200
// spatially-contiguous tiles (an 80-pixel-row band) so halo re-reads and
// the offconv->dconv handoff stay inside one 4MB L2.
__device__ inline void tile_map(int blk, int& b, int& ty0, int& tx0) {
  int t = (blk & 7) * 200 + (blk >> 3);
  b = t / 400;
  int r = t % 400;
  ty0 = (r / 10) * 4;
  tx0 = (r % 10) * 16;
}

// ---------------------------------------------------------------------------
// prep: prepacked MFMA B-fragments (K permuted to kappa = tap*8 + ch within
// each 8-ch chunk, 96-padded; taps 9..11 zero) + zero the BN partial slots.
// ---------------------------------------------------------------------------
__global__ void prep_kernel(const float* __restrict__ cw,
                            const float* __restrict__ ow,
                            unsigned short* __restrict__ Bp,
                            unsigned short* __restrict__ B2p,
                            float* __restrict__ part) {
  int i = blockIdx.x * 256 + threadIdx.x;
  if (i < 32768) part[i] = 0.f;
  if (i < 49152) {                      // dconv weights conv_w[n][c][t], nt 0..3
    int j = i & 7, l = (i >> 3) & 63, rest = i >> 9;
    int ki = rest % 24, nt = rest / 24;
    int kp = ki * 32 + ((l >> 4) << 3) + j;
    int chunk = kp / 96, kq = kp % 96;
    int t = kq >> 3, c = kq & 7;
    int n = nt * 16 + (l & 15);
    float v = (t < 9) ? cw[n * 576 + (chunk * 8 + c) * 9 + t] : 0.f;
    Bp[i] = bf16bits(v);
  }
  if (i < 24576) {                      // offconv weights, nt 0..1, n<18
    int j = i & 7, l = (i >> 3) & 63, rest = i >> 9;
    int ki = rest % 24, nt = rest / 24;
    int kp = ki * 32 + ((l >> 4) << 3) + j;
    int chunk = kp / 96, kq = kp % 96;
    int t = kq >> 3, c = kq & 7;
    int n = nt * 16 + (l & 15);
    float v = (t < 9 && n < 18) ? ow[n * 576 + (chunk * 8 + c) * 9 + t] : 0.f;
    B2p[i] = bf16bits(v);
  }
}

// ---------------------------------------------------------------------------
// FUSED offconv + dconv (round-1 verified structure: N-split waves + Af LDS
// exchange, 69.5us/64VGPR/no-spill). Single change vs round 1: patch
// staging re-tasked as (pixel, 4-channel half) so each task is 4 coalesced
// global dword loads (stride HWD) + ONE ds_write_b128 at 48B lane stride --
// the same conflict-free bank pattern as the interp reads. Replaces the
// per-channel b32 scatter stores (bank stride 12 -> 8-way conflict, the
// dominant share of round-1's 6.95M SQ_LDS_BANK_CONFLICT). Inner interp /
// MFMA / Af code is byte-identical to round 1 (every liveness increase there
// has spilled: rounds 2,3,6,7).
// LDS = patch 9072 + Af 12288 + offs 4608 = 25968 B -> 6 blocks/CU.
// ---------------------------------------------------------------------------
__global__ __launch_bounds__(256, 4) void fused_kernel(
    const float* __restrict__ x, const float* __restrict__ d,
    const bf16x8* __restrict__ Bp, const bf16x8* __restrict__ B2p,
    float* __restrict__ out, float* __restrict__ off_out,
    float* __restrict__ part) {
  int b, ty0, tx0;
  tile_map(blockIdx.x, b, ty0, tx0);
  const int tid = threadIdx.x;
  const int wv = tid >> 6, lane = tid & 63;
  const int lo = lane >> 4, li = lane & 15;
  const int px = li, py = wv;
  const int h = ty0 + py, w = tx0 + px;

  __shared__ float patch[189 * 12];    // phase1: 108x12 region; phase2: full
  __shared__ bf16x8 Af[768];
  __shared__ float offs_s[64 * 18];    // per-pixel 9 taps x (dy,dx)

  // ---- phase-2 x-staging: 378 tasks = (pixel p of 9x21, ch-half) ----
  // task -> 4 global dwords (c0..c0+3, stride HWD) + one b128 LDS store.
  int goff2[2], laddr2[2];
  bool inr2[2], ok2[2];
#pragma unroll
  for (int i = 0; i < 2; ++i) {
    int idx = tid + i * 256;
    int ch4 = idx / 189, p = idx % 189;
    int r = p / 21, col = p % 21;
    int gy = ty0 - 2 + r, gx = tx0 - 2 + col;
    inr2[i] = idx < 378;
    ok2[i] = inr2[i] && gy >= 0 && gy < HH && gx >= 0 && gx < WW;
    goff2[i] = ((b * 64 + ch4 * 4) * HH + gy) * WW + gx;
    laddr2[i] = p * 12 + ch4 * 4;      // 16B-aligned (48B pixel pitch)
  }

  // ================= phase 1: offconv =================
  f32x4 acc0{0.f, 0.f, 0.f, 0.f}, acc1{0.f, 0.f, 0.f, 0.f};
  const int ntA = wv >> 1, mh = wv & 1;
  {
    int poff[3];
    bool tre[3];
#pragma unroll
    for (int kk = 0; kk < 3; ++kk) {
      int t = kk * 4 + lo;
      tre[kk] = (t < 9);
      poff[kk] = tre[kk] ? ((py + t / 3) * 18 + px + t % 3) : 0;
    }

    // phase-1 staging: 216 tasks = (pixel p of 6x18, ch-half), 1/thread
    int goff1 = 0, laddr1 = 0;
    bool inr1 = tid < 216, ok1 = false;
    {
      int ch4 = tid / 108, p = tid % 108;
      int r = p / 18, col = p % 18;
      int gy = ty0 - 1 + r, gx = tx0 - 1 + col;
      ok1 = inr1 && gy >= 0 && gy < HH && gx >= 0 && gx < WW;
      goff1 = ((b * 64 + ch4 * 4) * HH + gy) * WW + gx;
      laddr1 = p * 12 + ch4 * 4;
    }
    float4 g1 = make_float4(0.f, 0.f, 0.f, 0.f);
    if (ok1) {
      const float* pp = d + goff1;
      g1 = make_float4(pp[0], pp[HWD], pp[2 * HWD], pp[3 * HWD]);
    }

    for (int chunk = 0; chunk < 8; ++chunk) {
      bf16x8 bw0 = B2p[((ntA * 24 + chunk * 3 + 0) << 6) + lane];
      bf16x8 bw1 = B2p[((ntA * 24 + chunk * 3 + 1) << 6) + lane];
      bf16x8 bw2 = B2p[((ntA * 24 + chunk * 3 + 2) << 6) + lane];
      if (inr1) *(float4*)&patch[laddr1] = g1;
      __syncthreads();
      int nco = ((chunk < 7) ? (chunk + 1) : 7) * CHSTRIDE;
      if (ok1) {
        const float* pp = d + goff1 + nco;
        g1 = make_float4(pp[0], pp[HWD], pp[2 * HWD], pp[3 * HWD]);
      }
#pragma unroll
      for (int kk = 0; kk < 3; ++kk) {
        union { bf16x8 v; unsigned u[4]; } a;
        if (tre[kk]) {
          const float* q = patch + poff[kk] * 12;
          float4 c0 = *(const float4*)(q);
          float4 c1 = *(const float4*)(q + 4);
          a.u[0] = pack2bf(c0.x, c0.y);
          a.u[1] = pack2bf(c0.z, c0.w);
          a.u[2] = pack2bf(c1.x, c1.y);
          a.u[3] = pack2bf(c1.z, c1.w);
        } else {
          a.u[0] = a.u[1] = a.u[2] = a.u[3] = 0u;
        }
        Af[((wv * 3 + kk) << 6) + lane] = a.v;
      }
      __syncthreads();
#pragma unroll
      for (int kk = 0; kk < 3; ++kk) {
        bf16x8 bw = (kk == 0) ? bw0 : (kk == 1) ? bw1 : bw2;
        acc0 = __builtin_amdgcn_mfma_f32_16x16x32_bf16(
            Af[(((mh * 2) * 3 + kk) << 6) + lane], bw, acc0, 0, 0, 0);
        acc1 = __builtin_amdgcn_mfma_f32_16x16x32_bf16(
            Af[(((mh * 2 + 1) * 3 + kk) << 6) + lane], bw, acc1, 0, 0, 0);
      }
    }
  }

  // issue the first x chunk now: HBM latency hides under the phase-1
  // epilogue + inter-phase barrier + offset unpack
  float4 gv4[2];
#pragma unroll
  for (int i = 0; i < 2; ++i) {
    gv4[i] = make_float4(0.f, 0.f, 0.f, 0.f);
    if (ok2[i]) {
      const float* pp = x + goff2[i];
      gv4[i] = make_float4(pp[0], pp[HWD], pp[2 * HWD], pp[3 * HWD]);
    }
  }

  {  // phase-1 epilogue: clamp, write global off_out + LDS offs_s
    const int n = ntA * 16 + li;
    if (n < 18) {
#pragma unroll
      for (int f = 0; f < 2; ++f) {
        int mf = mh * 2 + f;
        f32x4 a = f ? acc1 : acc0;
        float* po =
            off_out + ((b * 18 + n) * HH + ty0 + mf) * WW + tx0 + lo * 4;
        float4 v;
        v.x = fminf(1.f, fmaxf(-1.f, a[0]));
        v.y = fminf(1.f, fmaxf(-1.f, a[1]));
        v.z = fminf(1.f, fmaxf(-1.f, a[2]));
        v.w = fminf(1.f, fmaxf(-1.f, a[3]));
        *(float4*)po = v;
        int pix = mf * 16 + lo * 4;
        offs_s[(pix + 0) * 18 + n] = v.x;
        offs_s[(pix + 1) * 18 + n] = v.y;
        offs_s[(pix + 2) * 18 + n] = v.z;
        offs_s[(pix + 3) * 18 + n] = v.w;
      }
    }
  }
  __syncthreads();

  // ================= phase 2: dconv =================
  int bs[3];
  float W00[3], W01[3], W10[3], W11[3];
  bool tre[3];
#pragma unroll
  for (int kk = 0; kk < 3; ++kk) {
    int t = kk * 4 + lo;
    tre[kk] = (t < 9);
    if (tre[kk]) {
      float dy = offs_s[(py * 16 + px) * 18 + 2 * t];
      float dx = offs_s[(py * 16 + px) * 18 + 2 * t + 1];
      float pyf = (float)(h - 1 + t / 3) + dy;
      float pxf = (float)(w - 1 + t % 3) + dx;
      float y0 = floorf(pyf), x0 = floorf(pxf);
      float wy = pyf - y0, wx = pxf - x0;
      bs[kk] = ((int)y0 - (ty0 - 2)) * 21 + ((int)x0 - (tx0 - 2));
      W00[kk] = (1.f - wy) * (1.f - wx);
      W01[kk] = (1.f - wy) * wx;
      W10[kk] = wy * (1.f - wx);
      W11[kk] = wy * wx;
    } else {
      bs[kk] = 0;
      W00[kk] = W01[kk] = W10[kk] = W11[kk] = 0.f;
    }
  }

  f32x4 acc[4];
#pragma unroll
  for (int i = 0; i < 4; ++i) acc[i] = f32x4{0.f, 0.f, 0.f, 0.f};
  const int nt = wv;

  for (int chunk = 0; chunk < 8; ++chunk) {
    bf16x8 bw0 = Bp[((nt * 24 + chunk * 3 + 0) << 6) + lane];
    bf16x8 bw1 = Bp[((nt * 24 + chunk * 3 + 1) << 6) + lane];
    bf16x8 bw2 = Bp[((nt * 24 + chunk * 3 + 2) << 6) + lane];
#pragma unroll
    for (int i = 0; i < 2; ++i)
      if (inr2[i]) *(float4*)&patch[laddr2[i]] = gv4[i];
    __syncthreads();
    int nco = ((chunk < 7) ? (chunk + 1) : 7) * CHSTRIDE;
#pragma unroll
    for (int i = 0; i < 2; ++i) {
      if (ok2[i]) {
        const float* pp = x + goff2[i] + nco;
        gv4[i] = make_float4(pp[0], pp[HWD], pp[2 * HWD], pp[3 * HWD]);
      }
    }
#pragma unroll
    for (int kk = 0; kk < 3; ++kk) {
      union { bf16x8 v; unsigned u[4]; } a;
      if (tre[kk]) {
        const float* q = patch + bs[kk] * 12;
        float4 p00a = *(const float4*)(q);         // corner (0,0) ch0-3
        float4 p00b = *(const float4*)(q + 4);     //            ch4-7
        float4 p01a = *(const float4*)(q + 12);    // corner (0,1)
        float4 p01b = *(const float4*)(q + 16);
        float4 p10a = *(const float4*)(q + 252);   // corner (1,0): +21*12
        float4 p10b = *(const float4*)(q + 256);
        float4 p11a = *(const float4*)(q + 264);   // corner (1,1)
        float4 p11b = *(const float4*)(q + 268);
        float w0 = W00[kk], w1 = W01[kk], w2 = W10[kk], w3 = W11[kk];
        float v0 = fmaf(w3, p11a.x, fmaf(w2, p10a.x, fmaf(w1, p01a.x, w0 * p00a.x)));
        float v1 = fmaf(w3, p11a.y, fmaf(w2, p10a.y, fmaf(w1, p01a.y, w0 * p00a.y)));
        float v2 = fmaf(w3, p11a.z, fmaf(w2, p10a.z, fmaf(w1, p01a.z, w0 * p00a.z)));
        float v3 = fmaf(w3, p11a.w, fmaf(w2, p10a.w, fmaf(w1, p01a.w, w0 * p00a.w)));
        float v4 = fmaf(w3, p11b.x, fmaf(w2, p10b.x, fmaf(w1, p01b.x, w0 * p00b.x)));
        float v5 = fmaf(w3, p11b.y, fmaf(w2, p10b.y, fmaf(w1, p01b.y, w0 * p00b.y)));
        float v6 = fmaf(w3, p11b.z, fmaf(w2, p10b.z, fmaf(w1, p01b.z, w0 * p00b.z)));
        float v7 = fmaf(w3, p11b.w, fmaf(w2, p10b.w, fmaf(w1, p01b.w, w0 * p00b.w)));
        a.u[0] = pack2bf(v0, v1);
        a.u[1] = pack2bf(v2, v3);
        a.u[2] = pack2bf(v4, v5);
        a.u[3] = pack2bf(v6, v7);
      } else {
        a.u[0] = a.u[1] = a.u[2] = a.u[3] = 0u;
      }
      Af[((wv * 3 + kk) << 6) + lane] = a.v;
    }
    __syncthreads();
#pragma unroll
    for (int kk = 0; kk < 3; ++kk) {
      bf16x8 bw = (kk == 0) ? bw0 : (kk == 1) ? bw1 : bw2;
#pragma unroll
      for (int mf = 0; mf < 4; ++mf)
        acc[mf] = __builtin_amdgcn_mfma_f32_16x16x32_bf16(
            Af[((mf * 3 + kk) << 6) + lane], bw, acc[mf], 0, 0, 0);
    }
  }
  // epilogue: aligned float4 stores + fused BN partial sums
  const int n = nt * 16 + li;
  float s = 0.f, s2 = 0.f;
#pragma unroll
  for (int mf = 0; mf < 4; ++mf) {
    float* po = out + ((b * 64 + n) * HH + ty0 + mf) * WW + tx0 + lo * 4;
    *(float4*)po = make_float4(acc[mf][0], acc[mf][1], acc[mf][2], acc[mf][3]);
#pragma unroll
    for (int r = 0; r < 4; ++r) {
      float v = acc[mf][r];
      s += v;
      s2 = fmaf(v, v, s2);
    }
  }
  // reduce across the 4 lanes (lo=0..3) holding channel n
  s += __shfl_xor(s, 16);  s += __shfl_xor(s, 32);
  s2 += __shfl_xor(s2, 16); s2 += __shfl_xor(s2, 32);
  if (lo == 0) {
    int slot = blockIdx.x & (NSLOT - 1);
    atomicAdd(&part[n * NSLOT + slot], s);
    atomicAdd(&part[(64 + n) * NSLOT + slot], s2);
  }
}

// ---------------------------------------------------------------------------
// reduce BN partials: block j sums part[j][0..255] (f64) -> sums[j]
// ---------------------------------------------------------------------------
__global__ __launch_bounds__(256) void reduce_kernel(
    const float* __restrict__ part, double* __restrict__ sums) {
  const int j = blockIdx.x;
  __shared__ double sh[256];
  sh[threadIdx.x] = (double)part[j * NSLOT + threadIdx.x];
  __syncthreads();
  for (int t = 128; t > 0; t >>= 1) {
    if (threadIdx.x < t) sh[threadIdx.x] += sh[threadIdx.x + t];
    __syncthreads();
  }
  if (threadIdx.x == 0) sums[j] = sh[0];
}

// ---------------------------------------------------------------------------
// BN apply + ReLU, in place on d_out's conv region (float4 vectorized).
// ---------------------------------------------------------------------------
__global__ __launch_bounds__(256) void bnapply_kernel(
    float* __restrict__ out, const double* __restrict__ sums,
    const float* __restrict__ gamma, const float* __restrict__ beta) {
  const int i = blockIdx.x * 256 + threadIdx.x;
  if (i >= OUT_ELEMS / 4) return;
  const int o = (i / (HWD / 4)) & 63;
  const float n_inv = 1.0f / (float)(BB * HWD);
  float mean = (float)sums[o] * n_inv;
  float var = (float)sums[64 + o] * n_inv - mean * mean;
  float inv = gamma[o] * rsqrtf(var + EPSBN);
  float bt = beta[o];
  float4 v = ((float4*)out)[i];
  v.x = fmaxf(0.f, (v.x - mean) * inv + bt);
  v.y = fmaxf(0.f, (v.y - mean) * inv + bt);
  v.z = fmaxf(0.f, (v.z - mean) * inv + bt);
  v.w = fmaxf(0.f, (v.w - mean) * inv + bt);
  ((float4*)out)[i] = v;
}

extern "C" void kernel_launch(void* const* d_in, const int* in_sizes, int n_in,
                              void* d_out, int out_size, void* d_ws, size_t ws_size,
                              hipStream_t stream) {
  const float* x = (const float*)d_in[0];
  const float* d = (const float*)d_in[1];
  const float* ow = (const float*)d_in[2];
  const float* cw = (const float*)d_in[3];
  const float* gamma = (const float*)d_in[4];
  const float* beta = (const float*)d_in[5];

  float* out = (float*)d_out;
  float* off_out = out + OUT_ELEMS;

  // ws: sums double[128] | Bp ush[49152] | B2p ush[24576] | part f32[32768]
  double* sums = (double*)d_ws;
  unsigned short* Bp = (unsigned short*)((char*)d_ws + 1024);
  unsigned short* B2p = Bp + 49152;
  float* part = (float*)(B2p + 24576);

  prep_kernel<<<192, 256, 0, stream>>>(cw, ow, Bp, B2p, part);

  fused_kernel<<<1600, 256, 0, stream>>>(x, d, (const bf16x8*)Bp,
                                         (const bf16x8*)B2p, out, off_out,
                                         part);

  reduce_kernel<<<128, 256, 0, stream>>>(part, sums);
  bnapply_kernel<<<(OUT_ELEMS / 4 + 255) / 256, 256, 0, stream>>>(
      out, sums, gamma, beta);
}

// Round 10
// 157.949 us; speedup vs baseline: 1.9547x; 1.0031x over previous
//
#include <hip/hip_runtime.h>
#include <hip/hip_bf16.h>

#define BB 4
#define HH 160
#define WW 160
#define HWD (HH * WW)                   // 25600
#define OUT_ELEMS (BB * 64 * HWD)       // 6,553,600
#define OFF_ELEMS (BB * 18 * HWD)       // 1,843,200
#define EPSBN 1e-5f
#define CHSTRIDE (8 * HWD)              // 8-channel chunk stride
#define NSLOT 256                       // BN partial slots per channel-stat

typedef __attribute__((ext_vector_type(8))) short bf16x8;
typedef __attribute__((ext_vector_type(4))) float f32x4;

__device__ inline unsigned pack2bf(float a, float b) {
  __hip_bfloat162 h2 = __float22bfloat162_rn(float2{a, b});
  unsigned u;
  __builtin_memcpy(&u, &h2, 4);
  return u;
}
__device__ inline unsigned short bf16bits(float a) {
  __hip_bfloat16 h = __float2bfloat16(a);
  unsigned short u;
  __builtin_memcpy(&u, &h, 2);
  return u;
}

// LDS-only barrier: waits ds ops (lgkmcnt) but lets global prefetches stay
// in flight across the barrier. __syncthreads() would emit s_waitcnt
// vmcnt(0) before s_barrier, draining every prefetch ~150cy after issue --
// the dominant stall of the round-9 kernel (33 barriers/block). All
// barrier-ordered data here is LDS (patch, Af, offs_s); global loads are
// ordered by the compiler's vmcnt-before-use at their consumption point.
__device__ inline void ldsbar() {
  asm volatile("s_waitcnt lgkmcnt(0)" ::: "memory");
  __builtin_amdgcn_s_barrier();
}

// XCD-slab tile mapping: blk%8 = XCD (HW round-robin); each XCD owns 200
// spatially-contiguous tiles (an 80-pixel-row band) so halo re-reads and
// the offconv->dconv handoff stay inside one 4MB L2.
__device__ inline void tile_map(int blk, int& b, int& ty0, int& tx0) {
  int t = (blk & 7) * 200 + (blk >> 3);
  b = t / 400;
  int r = t % 400;
  ty0 = (r / 10) * 4;
  tx0 = (r % 10) * 16;
}

// ---------------------------------------------------------------------------
// prep: prepacked MFMA B-fragments (K permuted to kappa = tap*8 + ch within
// each 8-ch chunk, 96-padded; taps 9..11 zero) + zero the BN partial slots.
// ---------------------------------------------------------------------------
__global__ void prep_kernel(const float* __restrict__ cw,
                            const float* __restrict__ ow,
                            unsigned short* __restrict__ Bp,
                            unsigned short* __restrict__ B2p,
                            float* __restrict__ part) {
  int i = blockIdx.x * 256 + threadIdx.x;
  if (i < 32768) part[i] = 0.f;
  if (i < 49152) {                      // dconv weights conv_w[n][c][t], nt 0..3
    int j = i & 7, l = (i >> 3) & 63, rest = i >> 9;
    int ki = rest % 24, nt = rest / 24;
    int kp = ki * 32 + ((l >> 4) << 3) + j;
    int chunk = kp / 96, kq = kp % 96;
    int t = kq >> 3, c = kq & 7;
    int n = nt * 16 + (l & 15);
    float v = (t < 9) ? cw[n * 576 + (chunk * 8 + c) * 9 + t] : 0.f;
    Bp[i] = bf16bits(v);
  }
  if (i < 24576) {                      // offconv weights, nt 0..1, n<18
    int j = i & 7, l = (i >> 3) & 63, rest = i >> 9;
    int ki = rest % 24, nt = rest / 24;
    int kp = ki * 32 + ((l >> 4) << 3) + j;
    int chunk = kp / 96, kq = kp % 96;
    int t = kq >> 3, c = kq & 7;
    int n = nt * 16 + (l & 15);
    float v = (t < 9 && n < 18) ? ow[n * 576 + (chunk * 8 + c) * 9 + t] : 0.f;
    B2p[i] = bf16bits(v);
  }
}

// ---------------------------------------------------------------------------
// FUSED offconv + dconv (round-9 verified structure: N-split waves + Af LDS
// exchange + conflict-free b128 patch staging; 66.8us/60VGPR/no-spill/4.28M
// conflicts). Single change vs round 9: every __syncthreads() replaced by
// ldsbar() (lgkmcnt-only wait + raw s_barrier) so the chunk-ahead global
// prefetches of d/x and the bw weight loads are no longer force-drained at
// each barrier -- prefetch distance grows from ~150cy to a full chunk.
// Inner interp / MFMA / Af code byte-identical (liveness changes spill:
// rounds 2,3,6,7).
// LDS = patch 9072 + Af 12288 + offs 4608 = 25968 B -> 6 blocks/CU.
// ---------------------------------------------------------------------------
__global__ __launch_bounds__(256, 4) void fused_kernel(
    const float* __restrict__ x, const float* __restrict__ d,
    const bf16x8* __restrict__ Bp, const bf16x8* __restrict__ B2p,
    float* __restrict__ out, float* __restrict__ off_out,
    float* __restrict__ part) {
  int b, ty0, tx0;
  tile_map(blockIdx.x, b, ty0, tx0);
  const int tid = threadIdx.x;
  const int wv = tid >> 6, lane = tid & 63;
  const int lo = lane >> 4, li = lane & 15;
  const int px = li, py = wv;
  const int h = ty0 + py, w = tx0 + px;

  __shared__ float patch[189 * 12];    // phase1: 108x12 region; phase2: full
  __shared__ bf16x8 Af[768];
  __shared__ float offs_s[64 * 18];    // per-pixel 9 taps x (dy,dx)

  // ---- phase-2 x-staging: 378 tasks = (pixel p of 9x21, ch-half) ----
  // task -> 4 global dwords (c0..c0+3, stride HWD) + one b128 LDS store.
  int goff2[2], laddr2[2];
  bool inr2[2], ok2[2];
#pragma unroll
  for (int i = 0; i < 2; ++i) {
    int idx = tid + i * 256;
    int ch4 = idx / 189, p = idx % 189;
    int r = p / 21, col = p % 21;
    int gy = ty0 - 2 + r, gx = tx0 - 2 + col;
    inr2[i] = idx < 378;
    ok2[i] = inr2[i] && gy >= 0 && gy < HH && gx >= 0 && gx < WW;
    goff2[i] = ((b * 64 + ch4 * 4) * HH + gy) * WW + gx;
    laddr2[i] = p * 12 + ch4 * 4;      // 16B-aligned (48B pixel pitch)
  }

  // ================= phase 1: offconv =================
  f32x4 acc0{0.f, 0.f, 0.f, 0.f}, acc1{0.f, 0.f, 0.f, 0.f};
  const int ntA = wv >> 1, mh = wv & 1;
  {
    int poff[3];
    bool tre[3];
#pragma unroll
    for (int kk = 0; kk < 3; ++kk) {
      int t = kk * 4 + lo;
      tre[kk] = (t < 9);
      poff[kk] = tre[kk] ? ((py + t / 3) * 18 + px + t % 3) : 0;
    }

    // phase-1 staging: 216 tasks = (pixel p of 6x18, ch-half), 1/thread
    int goff1 = 0, laddr1 = 0;
    bool inr1 = tid < 216, ok1 = false;
    {
      int ch4 = tid / 108, p = tid % 108;
      int r = p / 18, col = p % 18;
      int gy = ty0 - 1 + r, gx = tx0 - 1 + col;
      ok1 = inr1 && gy >= 0 && gy < HH && gx >= 0 && gx < WW;
      goff1 = ((b * 64 + ch4 * 4) * HH + gy) * WW + gx;
      laddr1 = p * 12 + ch4 * 4;
    }
    float4 g1 = make_float4(0.f, 0.f, 0.f, 0.f);
    if (ok1) {
      const float* pp = d + goff1;
      g1 = make_float4(pp[0], pp[HWD], pp[2 * HWD], pp[3 * HWD]);
    }

    for (int chunk = 0; chunk < 8; ++chunk) {
      bf16x8 bw0 = B2p[((ntA * 24 + chunk * 3 + 0) << 6) + lane];
      bf16x8 bw1 = B2p[((ntA * 24 + chunk * 3 + 1) << 6) + lane];
      bf16x8 bw2 = B2p[((ntA * 24 + chunk * 3 + 2) << 6) + lane];
      if (inr1) *(float4*)&patch[laddr1] = g1;
      ldsbar();
      int nco = ((chunk < 7) ? (chunk + 1) : 7) * CHSTRIDE;
      if (ok1) {
        const float* pp = d + goff1 + nco;
        g1 = make_float4(pp[0], pp[HWD], pp[2 * HWD], pp[3 * HWD]);
      }
#pragma unroll
      for (int kk = 0; kk < 3; ++kk) {
        union { bf16x8 v; unsigned u[4]; } a;
        if (tre[kk]) {
          const float* q = patch + poff[kk] * 12;
          float4 c0 = *(const float4*)(q);
          float4 c1 = *(const float4*)(q + 4);
          a.u[0] = pack2bf(c0.x, c0.y);
          a.u[1] = pack2bf(c0.z, c0.w);
          a.u[2] = pack2bf(c1.x, c1.y);
          a.u[3] = pack2bf(c1.z, c1.w);
        } else {
          a.u[0] = a.u[1] = a.u[2] = a.u[3] = 0u;
        }
        Af[((wv * 3 + kk) << 6) + lane] = a.v;
      }
      ldsbar();
#pragma unroll
      for (int kk = 0; kk < 3; ++kk) {
        bf16x8 bw = (kk == 0) ? bw0 : (kk == 1) ? bw1 : bw2;
        acc0 = __builtin_amdgcn_mfma_f32_16x16x32_bf16(
            Af[(((mh * 2) * 3 + kk) << 6) + lane], bw, acc0, 0, 0, 0);
        acc1 = __builtin_amdgcn_mfma_f32_16x16x32_bf16(
            Af[(((mh * 2 + 1) * 3 + kk) << 6) + lane], bw, acc1, 0, 0, 0);
      }
    }
  }

  // issue the first x chunk now: HBM latency hides under the phase-1
  // epilogue + inter-phase barrier + offset unpack
  float4 gv4[2];
#pragma unroll
  for (int i = 0; i < 2; ++i) {
    gv4[i] = make_float4(0.f, 0.f, 0.f, 0.f);
    if (ok2[i]) {
      const float* pp = x + goff2[i];
      gv4[i] = make_float4(pp[0], pp[HWD], pp[2 * HWD], pp[3 * HWD]);
    }
  }

  {  // phase-1 epilogue: clamp, write global off_out + LDS offs_s
    const int n = ntA * 16 + li;
    if (n < 18) {
#pragma unroll
      for (int f = 0; f < 2; ++f) {
        int mf = mh * 2 + f;
        f32x4 a = f ? acc1 : acc0;
        float* po =
            off_out + ((b * 18 + n) * HH + ty0 + mf) * WW + tx0 + lo * 4;
        float4 v;
        v.x = fminf(1.f, fmaxf(-1.f, a[0]));
        v.y = fminf(1.f, fmaxf(-1.f, a[1]));
        v.z = fminf(1.f, fmaxf(-1.f, a[2]));
        v.w = fminf(1.f, fmaxf(-1.f, a[3]));
        *(float4*)po = v;
        int pix = mf * 16 + lo * 4;
        offs_s[(pix + 0) * 18 + n] = v.x;
        offs_s[(pix + 1) * 18 + n] = v.y;
        offs_s[(pix + 2) * 18 + n] = v.z;
        offs_s[(pix + 3) * 18 + n] = v.w;
      }
    }
  }
  ldsbar();

  // ================= phase 2: dconv =================
  int bs[3];
  float W00[3], W01[3], W10[3], W11[3];
  bool tre[3];
#pragma unroll
  for (int kk = 0; kk < 3; ++kk) {
    int t = kk * 4 + lo;
    tre[kk] = (t < 9);
    if (tre[kk]) {
      float dy = offs_s[(py * 16 + px) * 18 + 2 * t];
      float dx = offs_s[(py * 16 + px) * 18 + 2 * t + 1];
      float pyf = (float)(h - 1 + t / 3) + dy;
      float pxf = (float)(w - 1 + t % 3) + dx;
      float y0 = floorf(pyf), x0 = floorf(pxf);
      float wy = pyf - y0, wx = pxf - x0;
      bs[kk] = ((int)y0 - (ty0 - 2)) * 21 + ((int)x0 - (tx0 - 2));
      W00[kk] = (1.f - wy) * (1.f - wx);
      W01[kk] = (1.f - wy) * wx;
      W10[kk] = wy * (1.f - wx);
      W11[kk] = wy * wx;
    } else {
      bs[kk] = 0;
      W00[kk] = W01[kk] = W10[kk] = W11[kk] = 0.f;
    }
  }

  f32x4 acc[4];
#pragma unroll
  for (int i = 0; i < 4; ++i) acc[i] = f32x4{0.f, 0.f, 0.f, 0.f};
  const int nt = wv;

  for (int chunk = 0; chunk < 8; ++chunk) {
    bf16x8 bw0 = Bp[((nt * 24 + chunk * 3 + 0) << 6) + lane];
    bf16x8 bw1 = Bp[((nt * 24 + chunk * 3 + 1) << 6) + lane];
    bf16x8 bw2 = Bp[((nt * 24 + chunk * 3 + 2) << 6) + lane];
#pragma unroll
    for (int i = 0; i < 2; ++i)
      if (inr2[i]) *(float4*)&patch[laddr2[i]] = gv4[i];
    ldsbar();
    int nco = ((chunk < 7) ? (chunk + 1) : 7) * CHSTRIDE;
#pragma unroll
    for (int i = 0; i < 2; ++i) {
      if (ok2[i]) {
        const float* pp = x + goff2[i] + nco;
        gv4[i] = make_float4(pp[0], pp[HWD], pp[2 * HWD], pp[3 * HWD]);
      }
    }
#pragma unroll
    for (int kk = 0; kk < 3; ++kk) {
      union { bf16x8 v; unsigned u[4]; } a;
      if (tre[kk]) {
        const float* q = patch + bs[kk] * 12;
        float4 p00a = *(const float4*)(q);         // corner (0,0) ch0-3
        float4 p00b = *(const float4*)(q + 4);     //            ch4-7
        float4 p01a = *(const float4*)(q + 12);    // corner (0,1)
        float4 p01b = *(const float4*)(q + 16);
        float4 p10a = *(const float4*)(q + 252);   // corner (1,0): +21*12
        float4 p10b = *(const float4*)(q + 256);
        float4 p11a = *(const float4*)(q + 264);   // corner (1,1)
        float4 p11b = *(const float4*)(q + 268);
        float w0 = W00[kk], w1 = W01[kk], w2 = W10[kk], w3 = W11[kk];
        float v0 = fmaf(w3, p11a.x, fmaf(w2, p10a.x, fmaf(w1, p01a.x, w0 * p00a.x)));
        float v1 = fmaf(w3, p11a.y, fmaf(w2, p10a.y, fmaf(w1, p01a.y, w0 * p00a.y)));
        float v2 = fmaf(w3, p11a.z, fmaf(w2, p10a.z, fmaf(w1, p01a.z, w0 * p00a.z)));
        float v3 = fmaf(w3, p11a.w, fmaf(w2, p10a.w, fmaf(w1, p01a.w, w0 * p00a.w)));
        float v4 = fmaf(w3, p11b.x, fmaf(w2, p10b.x, fmaf(w1, p01b.x, w0 * p00b.x)));
        float v5 = fmaf(w3, p11b.y, fmaf(w2, p10b.y, fmaf(w1, p01b.y, w0 * p00b.y)));
        float v6 = fmaf(w3, p11b.z, fmaf(w2, p10b.z, fmaf(w1, p01b.z, w0 * p00b.z)));
        float v7 = fmaf(w3, p11b.w, fmaf(w2, p10b.w, fmaf(w1, p01b.w, w0 * p00b.w)));
        a.u[0] = pack2bf(v0, v1);
        a.u[1] = pack2bf(v2, v3);
        a.u[2] = pack2bf(v4, v5);
        a.u[3] = pack2bf(v6, v7);
      } else {
        a.u[0] = a.u[1] = a.u[2] = a.u[3] = 0u;
      }
      Af[((wv * 3 + kk) << 6) + lane] = a.v;
    }
    ldsbar();
#pragma unroll
    for (int kk = 0; kk < 3; ++kk) {
      bf16x8 bw = (kk == 0) ? bw0 : (kk == 1) ? bw1 : bw2;
#pragma unroll
      for (int mf = 0; mf < 4; ++mf)
        acc[mf] = __builtin_amdgcn_mfma_f32_16x16x32_bf16(
            Af[((mf * 3 + kk) << 6) + lane], bw, acc[mf], 0, 0, 0);
    }
  }
  // epilogue: aligned float4 stores + fused BN partial sums
  const int n = nt * 16 + li;
  float s = 0.f, s2 = 0.f;
#pragma unroll
  for (int mf = 0; mf < 4; ++mf) {
    float* po = out + ((b * 64 + n) * HH + ty0 + mf) * WW + tx0 + lo * 4;
    *(float4*)po = make_float4(acc[mf][0], acc[mf][1], acc[mf][2], acc[mf][3]);
#pragma unroll
    for (int r = 0; r < 4; ++r) {
      float v = acc[mf][r];
      s += v;
      s2 = fmaf(v, v, s2);
    }
  }
  // reduce across the 4 lanes (lo=0..3) holding channel n
  s += __shfl_xor(s, 16);  s += __shfl_xor(s, 32);
  s2 += __shfl_xor(s2, 16); s2 += __shfl_xor(s2, 32);
  if (lo == 0) {
    int slot = blockIdx.x & (NSLOT - 1);
    atomicAdd(&part[n * NSLOT + slot], s);
    atomicAdd(&part[(64 + n) * NSLOT + slot], s2);
  }
}

// ---------------------------------------------------------------------------
// reduce BN partials: block j sums part[j][0..255] (f64) -> sums[j]
// ---------------------------------------------------------------------------
__global__ __launch_bounds__(256) void reduce_kernel(
    const float* __restrict__ part, double* __restrict__ sums) {
  const int j = blockIdx.x;
  __shared__ double sh[256];
  sh[threadIdx.x] = (double)part[j * NSLOT + threadIdx.x];
  __syncthreads();
  for (int t = 128; t > 0; t >>= 1) {
    if (threadIdx.x < t) sh[threadIdx.x] += sh[threadIdx.x + t];
    __syncthreads();
  }
  if (threadIdx.x == 0) sums[j] = sh[0];
}

// ---------------------------------------------------------------------------
// BN apply + ReLU, in place on d_out's conv region (float4 vectorized).
// ---------------------------------------------------------------------------
__global__ __launch_bounds__(256) void bnapply_kernel(
    float* __restrict__ out, const double* __restrict__ sums,
    const float* __restrict__ gamma, const float* __restrict__ beta) {
  const int i = blockIdx.x * 256 + threadIdx.x;
  if (i >= OUT_ELEMS / 4) return;
  const int o = (i / (HWD / 4)) & 63;
  const float n_inv = 1.0f / (float)(BB * HWD);
  float mean = (float)sums[o] * n_inv;
  float var = (float)sums[64 + o] * n_inv - mean * mean;
  float inv = gamma[o] * rsqrtf(var + EPSBN);
  float bt = beta[o];
  float4 v = ((float4*)out)[i];
  v.x = fmaxf(0.f, (v.x - mean) * inv + bt);
  v.y = fmaxf(0.f, (v.y - mean) * inv + bt);
  v.z = fmaxf(0.f, (v.z - mean) * inv + bt);
  v.w = fmaxf(0.f, (v.w - mean) * inv + bt);
  ((float4*)out)[i] = v;
}

extern "C" void kernel_launch(void* const* d_in, const int* in_sizes, int n_in,
                              void* d_out, int out_size, void* d_ws, size_t ws_size,
                              hipStream_t stream) {
  const float* x = (const float*)d_in[0];
  const float* d = (const float*)d_in[1];
  const float* ow = (const float*)d_in[2];
  const float* cw = (const float*)d_in[3];
  const float* gamma = (const float*)d_in[4];
  const float* beta = (const float*)d_in[5];

  float* out = (float*)d_out;
  float* off_out = out + OUT_ELEMS;

  // ws: sums double[128] | Bp ush[49152] | B2p ush[24576] | part f32[32768]
  double* sums = (double*)d_ws;
  unsigned short* Bp = (unsigned short*)((char*)d_ws + 1024);
  unsigned short* B2p = Bp + 49152;
  float* part = (float*)(B2p + 24576);

  prep_kernel<<<192, 256, 0, stream>>>(cw, ow, Bp, B2p, part);

  fused_kernel<<<1600, 256, 0, stream>>>(x, d, (const bf16x8*)Bp,
                                         (const bf16x8*)B2p, out, off_out,
                                         part);

  reduce_kernel<<<128, 256, 0, stream>>>(part, sums);
  bnapply_kernel<<<(OUT_ELEMS / 4 + 255) / 256, 256, 0, stream>>>(
      out, sums, gamma, beta);
}

// Round 12
// 154.299 us; speedup vs baseline: 2.0010x; 1.0237x over previous
//
#include <hip/hip_runtime.h>
#include <hip/hip_bf16.h>

#define BB 4
#define HH 160
#define WW 160
#define HWD (HH * WW)                   // 25600
#define OUT_ELEMS (BB * 64 * HWD)       // 6,553,600
#define OFF_ELEMS (BB * 18 * HWD)       // 1,843,200
#define EPSBN 1e-5f
#define CHSTRIDE (8 * HWD)              // 8-channel chunk stride
#define NSLOT 256                       // BN partial slots per channel-stat

typedef __attribute__((ext_vector_type(8))) _Float16 f16x8;
typedef __attribute__((ext_vector_type(4))) float f32x4;

__device__ inline unsigned short f16bits(float a) {
  _Float16 h = (_Float16)a;
  unsigned short u;
  __builtin_memcpy(&u, &h, 2);
  return u;
}

// pack two f32 -> 2x f16 (v_cvt_pkrtz_f16_f32), returned as raw u32 bits
__device__ inline unsigned pkrtz(float a, float b) {
  __fp16 __attribute__((ext_vector_type(2))) t =
      __builtin_amdgcn_cvt_pkrtz(a, b);
  unsigned u;
  __builtin_memcpy(&u, &t, 4);
  return u;
}

// load 8 channel values (stride HWD) and convert to packed f16
__device__ inline f16x8 load8cvt(const float* pp) {
  union { f16x8 v; unsigned u[4]; } r;
  r.u[0] = pkrtz(pp[0], pp[HWD]);
  r.u[1] = pkrtz(pp[2 * HWD], pp[3 * HWD]);
  r.u[2] = pkrtz(pp[4 * HWD], pp[5 * HWD]);
  r.u[3] = pkrtz(pp[6 * HWD], pp[7 * HWD]);
  return r.v;
}

// LDS-only barrier (round-10, neutral but harmless): lgkmcnt wait + barrier.
__device__ inline void ldsbar() {
  asm volatile("s_waitcnt lgkmcnt(0)" ::: "memory");
  __builtin_amdgcn_s_barrier();
}

// XCD-slab tile mapping: blk%8 = XCD (HW round-robin); each XCD owns 200
// spatially-contiguous tiles (an 80-pixel-row band) so halo re-reads and
// the offconv->dconv handoff stay inside one 4MB L2.
__device__ inline void tile_map(int blk, int& b, int& ty0, int& tx0) {
  int t = (blk & 7) * 200 + (blk >> 3);
  b = t / 400;
  int r = t % 400;
  ty0 = (r / 10) * 4;
  tx0 = (r % 10) * 16;
}

// ---------------------------------------------------------------------------
// prep: prepacked MFMA B-fragments in FP16 (K permuted to kappa = tap*8 + ch
// within each 8-ch chunk, 96-padded; taps 9..11 zero) + zero BN partials.
// ---------------------------------------------------------------------------
__global__ void prep_kernel(const float* __restrict__ cw,
                            const float* __restrict__ ow,
                            unsigned short* __restrict__ Bp,
                            unsigned short* __restrict__ B2p,
                            float* __restrict__ part) {
  int i = blockIdx.x * 256 + threadIdx.x;
  if (i < 32768) part[i] = 0.f;
  if (i < 49152) {                      // dconv weights conv_w[n][c][t], nt 0..3
    int j = i & 7, l = (i >> 3) & 63, rest = i >> 9;
    int ki = rest % 24, nt = rest / 24;
    int kp = ki * 32 + ((l >> 4) << 3) + j;
    int chunk = kp / 96, kq = kp % 96;
    int t = kq >> 3, c = kq & 7;
    int n = nt * 16 + (l & 15);
    float v = (t < 9) ? cw[n * 576 + (chunk * 8 + c) * 9 + t] : 0.f;
    Bp[i] = f16bits(v);
  }
  if (i < 24576) {                      // offconv weights, nt 0..1, n<18
    int j = i & 7, l = (i >> 3) & 63, rest = i >> 9;
    int ki = rest % 24, nt = rest / 24;
    int kp = ki * 32 + ((l >> 4) << 3) + j;
    int chunk = kp / 96, kq = kp % 96;
    int t = kq >> 3, c = kq & 7;
    int n = nt * 16 + (l & 15);
    float v = (t < 9 && n < 18) ? ow[n * 576 + (chunk * 8 + c) * 9 + t] : 0.f;
    B2p[i] = f16bits(v);
  }
}

// ---------------------------------------------------------------------------
// FUSED offconv + dconv, FP16 data path. Round-10 structure (N-split waves +
// Af exchange + b128 staging + ldsbar) with the patch, interp arithmetic,
// A/B fragments and MFMA all switched f32/bf16 -> f16:
//  - patch 16B/pixel (was 32B): interp reads 8->4 ds_read_b128 per kk,
//    patch writes halved. The kernel is LDS-pipe-bound (round-9/10 evidence:
//    conflict fix -38% -> -3us, barrier fix ~0); this cuts phase-2 LDS
//    traffic ~30% and phase-1 ~35%.
//  - interp in packed f16 (v_pk_mul/fma_f16): ~16 ops/kk vs ~40 scalar, and
//    the result IS the A-fragment (no pack2bf). Phase-1 A-build is a copy.
//  - f16 (10-bit mantissa) >= bf16 (7-bit) precision everywhere it replaces.
// LDS = patch 3024 + Af 12288 + offs 4608 = 19920 B. Liveness strictly
// lower than round 10 (corner reads 32->16 VGPRs): no spill risk.
// ---------------------------------------------------------------------------
__global__ __launch_bounds__(256, 4) void fused_kernel(
    const float* __restrict__ x, const float* __restrict__ d,
    const f16x8* __restrict__ Bp, const f16x8* __restrict__ B2p,
    float* __restrict__ out, float* __restrict__ off_out,
    float* __restrict__ part) {
  int b, ty0, tx0;
  tile_map(blockIdx.x, b, ty0, tx0);
  const int tid = threadIdx.x;
  const int wv = tid >> 6, lane = tid & 63;
  const int lo = lane >> 4, li = lane & 15;
  const int px = li, py = wv;
  const int h = ty0 + py, w = tx0 + px;

  __shared__ __align__(16) _Float16 patch[189 * 8];  // ph1: 108 px; ph2: all
  __shared__ f16x8 Af[768];
  __shared__ float offs_s[64 * 18];    // per-pixel 9 taps x (dy,dx)

  const f16x8 zero8 = {(_Float16)0, (_Float16)0, (_Float16)0, (_Float16)0,
                       (_Float16)0, (_Float16)0, (_Float16)0, (_Float16)0};

  // ---- phase-2 x-staging: 189 tasks = one 9x21 pixel each (8ch) ----
  int goff2 = 0, laddr2 = 0;
  bool inr2 = tid < 189, ok2 = false;
  {
    int p = tid;
    int r = p / 21, col = p % 21;
    int gy = ty0 - 2 + r, gx = tx0 - 2 + col;
    ok2 = inr2 && gy >= 0 && gy < HH && gx >= 0 && gx < WW;
    goff2 = ((b * 64) * HH + gy) * WW + gx;
    laddr2 = p * 8;                    // 16B-aligned
  }

  // ================= phase 1: offconv =================
  f32x4 acc0{0.f, 0.f, 0.f, 0.f}, acc1{0.f, 0.f, 0.f, 0.f};
  const int ntA = wv >> 1, mh = wv & 1;
  {
    int poff[3];
    bool tre[3];
#pragma unroll
    for (int kk = 0; kk < 3; ++kk) {
      int t = kk * 4 + lo;
      tre[kk] = (t < 9);
      poff[kk] = tre[kk] ? ((py + t / 3) * 18 + px + t % 3) : 0;
    }

    // phase-1 staging: 108 tasks = one 6x18 pixel each (8ch)
    int goff1 = 0, laddr1 = 0;
    bool inr1 = tid < 108, ok1 = false;
    {
      int p = tid;
      int r = p / 18, col = p % 18;
      int gy = ty0 - 1 + r, gx = tx0 - 1 + col;
      ok1 = inr1 && gy >= 0 && gy < HH && gx >= 0 && gx < WW;
      goff1 = ((b * 64) * HH + gy) * WW + gx;
      laddr1 = p * 8;
    }
    f16x8 g1 = zero8;
    if (ok1) g1 = load8cvt(d + goff1);

    for (int chunk = 0; chunk < 8; ++chunk) {
      f16x8 bw0 = B2p[((ntA * 24 + chunk * 3 + 0) << 6) + lane];
      f16x8 bw1 = B2p[((ntA * 24 + chunk * 3 + 1) << 6) + lane];
      f16x8 bw2 = B2p[((ntA * 24 + chunk * 3 + 2) << 6) + lane];
      if (inr1) *(f16x8*)&patch[laddr1] = g1;
      ldsbar();
      int nco = ((chunk < 7) ? (chunk + 1) : 7) * CHSTRIDE;
      if (ok1) g1 = load8cvt(d + goff1 + nco);
#pragma unroll
      for (int kk = 0; kk < 3; ++kk) {
        f16x8 av = tre[kk] ? *(const f16x8*)(patch + poff[kk] * 8) : zero8;
        Af[((wv * 3 + kk) << 6) + lane] = av;
      }
      ldsbar();
#pragma unroll
      for (int kk = 0; kk < 3; ++kk) {
        f16x8 bw = (kk == 0) ? bw0 : (kk == 1) ? bw1 : bw2;
        acc0 = __builtin_amdgcn_mfma_f32_16x16x32_f16(
            Af[(((mh * 2) * 3 + kk) << 6) + lane], bw, acc0, 0, 0, 0);
        acc1 = __builtin_amdgcn_mfma_f32_16x16x32_f16(
            Af[(((mh * 2 + 1) * 3 + kk) << 6) + lane], bw, acc1, 0, 0, 0);
      }
    }
  }

  // issue the first x chunk now: HBM latency hides under the phase-1
  // epilogue + inter-phase barrier + offset unpack
  f16x8 gv = zero8;
  if (ok2) gv = load8cvt(x + goff2);

  {  // phase-1 epilogue: clamp, write global off_out + LDS offs_s
    const int n = ntA * 16 + li;
    if (n < 18) {
#pragma unroll
      for (int f = 0; f < 2; ++f) {
        int mf = mh * 2 + f;
        f32x4 a = f ? acc1 : acc0;
        float* po =
            off_out + ((b * 18 + n) * HH + ty0 + mf) * WW + tx0 + lo * 4;
        float4 v;
        v.x = fminf(1.f, fmaxf(-1.f, a[0]));
        v.y = fminf(1.f, fmaxf(-1.f, a[1]));
        v.z = fminf(1.f, fmaxf(-1.f, a[2]));
        v.w = fminf(1.f, fmaxf(-1.f, a[3]));
        *(float4*)po = v;
        int pix = mf * 16 + lo * 4;
        offs_s[(pix + 0) * 18 + n] = v.x;
        offs_s[(pix + 1) * 18 + n] = v.y;
        offs_s[(pix + 2) * 18 + n] = v.z;
        offs_s[(pix + 3) * 18 + n] = v.w;
      }
    }
  }
  ldsbar();

  // ================= phase 2: dconv =================
  int bs[3];
  float W00[3], W01[3], W10[3], W11[3];
  bool tre[3];
#pragma unroll
  for (int kk = 0; kk < 3; ++kk) {
    int t = kk * 4 + lo;
    tre[kk] = (t < 9);
    if (tre[kk]) {
      float dy = offs_s[(py * 16 + px) * 18 + 2 * t];
      float dx = offs_s[(py * 16 + px) * 18 + 2 * t + 1];
      float pyf = (float)(h - 1 + t / 3) + dy;
      float pxf = (float)(w - 1 + t % 3) + dx;
      float y0 = floorf(pyf), x0 = floorf(pxf);
      float wy = pyf - y0, wx = pxf - x0;
      bs[kk] = ((int)y0 - (ty0 - 2)) * 21 + ((int)x0 - (tx0 - 2));
      W00[kk] = (1.f - wy) * (1.f - wx);
      W01[kk] = (1.f - wy) * wx;
      W10[kk] = wy * (1.f - wx);
      W11[kk] = wy * wx;
    } else {
      bs[kk] = 0;
      W00[kk] = W01[kk] = W10[kk] = W11[kk] = 0.f;
    }
  }

  f32x4 acc[4];
#pragma unroll
  for (int i = 0; i < 4; ++i) acc[i] = f32x4{0.f, 0.f, 0.f, 0.f};
  const int nt = wv;

  for (int chunk = 0; chunk < 8; ++chunk) {
    f16x8 bw0 = Bp[((nt * 24 + chunk * 3 + 0) << 6) + lane];
    f16x8 bw1 = Bp[((nt * 24 + chunk * 3 + 1) << 6) + lane];
    f16x8 bw2 = Bp[((nt * 24 + chunk * 3 + 2) << 6) + lane];
    if (inr2) *(f16x8*)&patch[laddr2] = gv;
    ldsbar();
    int nco = ((chunk < 7) ? (chunk + 1) : 7) * CHSTRIDE;
    if (ok2) gv = load8cvt(x + goff2 + nco);
#pragma unroll
    for (int kk = 0; kk < 3; ++kk) {
      f16x8 av;
      if (tre[kk]) {
        const _Float16* q = patch + bs[kk] * 8;
        f16x8 p00 = *(const f16x8*)(q);            // corner (0,0), 8 ch
        f16x8 p01 = *(const f16x8*)(q + 8);        // corner (0,1)
        f16x8 p10 = *(const f16x8*)(q + 168);      // corner (1,0): +21*8
        f16x8 p11 = *(const f16x8*)(q + 176);      // corner (1,1)
        _Float16 w0 = (_Float16)W00[kk], w1 = (_Float16)W01[kk];
        _Float16 w2 = (_Float16)W10[kk], w3 = (_Float16)W11[kk];
        f16x8 w0v = {w0, w0, w0, w0, w0, w0, w0, w0};
        f16x8 w1v = {w1, w1, w1, w1, w1, w1, w1, w1};
        f16x8 w2v = {w2, w2, w2, w2, w2, w2, w2, w2};
        f16x8 w3v = {w3, w3, w3, w3, w3, w3, w3, w3};
        av = p00 * w0v + p01 * w1v + p10 * w2v + p11 * w3v;
      } else {
        av = zero8;
      }
      Af[((wv * 3 + kk) << 6) + lane] = av;
    }
    ldsbar();
#pragma unroll
    for (int kk = 0; kk < 3; ++kk) {
      f16x8 bw = (kk == 0) ? bw0 : (kk == 1) ? bw1 : bw2;
#pragma unroll
      for (int mf = 0; mf < 4; ++mf)
        acc[mf] = __builtin_amdgcn_mfma_f32_16x16x32_f16(
            Af[((mf * 3 + kk) << 6) + lane], bw, acc[mf], 0, 0, 0);
    }
  }
  // epilogue: aligned float4 stores + fused BN partial sums
  const int n = nt * 16 + li;
  float s = 0.f, s2 = 0.f;
#pragma unroll
  for (int mf = 0; mf < 4; ++mf) {
    float* po = out + ((b * 64 + n) * HH + ty0 + mf) * WW + tx0 + lo * 4;
    *(float4*)po = make_float4(acc[mf][0], acc[mf][1], acc[mf][2], acc[mf][3]);
#pragma unroll
    for (int r = 0; r < 4; ++r) {
      float v = acc[mf][r];
      s += v;
      s2 = fmaf(v, v, s2);
    }
  }
  // reduce across the 4 lanes (lo=0..3) holding channel n
  s += __shfl_xor(s, 16);  s += __shfl_xor(s, 32);
  s2 += __shfl_xor(s2, 16); s2 += __shfl_xor(s2, 32);
  if (lo == 0) {
    int slot = blockIdx.x & (NSLOT - 1);
    atomicAdd(&part[n * NSLOT + slot], s);
    atomicAdd(&part[(64 + n) * NSLOT + slot], s2);
  }
}

// ---------------------------------------------------------------------------
// reduce BN partials: block j sums part[j][0..255] (f64) -> sums[j]
// ---------------------------------------------------------------------------
__global__ __launch_bounds__(256) void reduce_kernel(
    const float* __restrict__ part, double* __restrict__ sums) {
  const int j = blockIdx.x;
  __shared__ double sh[256];
  sh[threadIdx.x] = (double)part[j * NSLOT + threadIdx.x];
  __syncthreads();
  for (int t = 128; t > 0; t >>= 1) {
    if (threadIdx.x < t) sh[threadIdx.x] += sh[threadIdx.x + t];
    __syncthreads();
  }
  if (threadIdx.x == 0) sums[j] = sh[0];
}

// ---------------------------------------------------------------------------
// BN apply + ReLU, in place on d_out's conv region (float4 vectorized).
// ---------------------------------------------------------------------------
__global__ __launch_bounds__(256) void bnapply_kernel(
    float* __restrict__ out, const double* __restrict__ sums,
    const float* __restrict__ gamma, const float* __restrict__ beta) {
  const int i = blockIdx.x * 256 + threadIdx.x;
  if (i >= OUT_ELEMS / 4) return;
  const int o = (i / (HWD / 4)) & 63;
  const float n_inv = 1.0f / (float)(BB * HWD);
  float mean = (float)sums[o] * n_inv;
  float var = (float)sums[64 + o] * n_inv - mean * mean;
  float inv = gamma[o] * rsqrtf(var + EPSBN);
  float bt = beta[o];
  float4 v = ((float4*)out)[i];
  v.x = fmaxf(0.f, (v.x - mean) * inv + bt);
  v.y = fmaxf(0.f, (v.y - mean) * inv + bt);
  v.z = fmaxf(0.f, (v.z - mean) * inv + bt);
  v.w = fmaxf(0.f, (v.w - mean) * inv + bt);
  ((float4*)out)[i] = v;
}

extern "C" void kernel_launch(void* const* d_in, const int* in_sizes, int n_in,
                              void* d_out, int out_size, void* d_ws, size_t ws_size,
                              hipStream_t stream) {
  const float* x = (const float*)d_in[0];
  const float* d = (const float*)d_in[1];
  const float* ow = (const float*)d_in[2];
  const float* cw = (const float*)d_in[3];
  const float* gamma = (const float*)d_in[4];
  const float* beta = (const float*)d_in[5];

  float* out = (float*)d_out;
  float* off_out = out + OUT_ELEMS;

  // ws: sums double[128] | Bp ush[49152] | B2p ush[24576] | part f32[32768]
  double* sums = (double*)d_ws;
  unsigned short* Bp = (unsigned short*)((char*)d_ws + 1024);
  unsigned short* B2p = Bp + 49152;
  float* part = (float*)(B2p + 24576);

  prep_kernel<<<192, 256, 0, stream>>>(cw, ow, Bp, B2p, part);

  fused_kernel<<<1600, 256, 0, stream>>>(x, d, (const f16x8*)Bp,
                                         (const f16x8*)B2p, out, off_out,
                                         part);

  reduce_kernel<<<128, 256, 0, stream>>>(part, sums);
  bnapply_kernel<<<(OUT_ELEMS / 4 + 255) / 256, 256, 0, stream>>>(
      out, sums, gamma, beta);
}

// Round 13
// 152.773 us; speedup vs baseline: 2.0209x; 1.0100x over previous
//
#include <hip/hip_runtime.h>
#include <hip/hip_bf16.h>

#define BB 4
#define HH 160
#define WW 160
#define HWD (HH * WW)                   // 25600
#define OUT_ELEMS (BB * 64 * HWD)       // 6,553,600
#define OFF_ELEMS (BB * 18 * HWD)       // 1,843,200
#define EPSBN 1e-5f
#define CHSTRIDE (8 * HWD)              // 8-channel chunk stride
#define NSLOT 256                       // BN partial slots per channel-stat

typedef __attribute__((ext_vector_type(8))) _Float16 f16x8;
typedef __attribute__((ext_vector_type(4))) float f32x4;

__device__ inline unsigned short f16bits(float a) {
  _Float16 h = (_Float16)a;
  unsigned short u;
  __builtin_memcpy(&u, &h, 2);
  return u;
}

// pack two f32 -> 2x f16 (v_cvt_pkrtz_f16_f32), returned as raw u32 bits
__device__ inline unsigned pkrtz(float a, float b) {
  __fp16 __attribute__((ext_vector_type(2))) t =
      __builtin_amdgcn_cvt_pkrtz(a, b);
  unsigned u;
  __builtin_memcpy(&u, &t, 4);
  return u;
}

// load 8 channel values (stride HWD) and convert to packed f16
__device__ inline f16x8 load8cvt(const float* pp) {
  union { f16x8 v; unsigned u[4]; } r;
  r.u[0] = pkrtz(pp[0], pp[HWD]);
  r.u[1] = pkrtz(pp[2 * HWD], pp[3 * HWD]);
  r.u[2] = pkrtz(pp[4 * HWD], pp[5 * HWD]);
  r.u[3] = pkrtz(pp[6 * HWD], pp[7 * HWD]);
  return r.v;
}

// LDS-only barrier: lgkmcnt wait + raw barrier (global prefetches stay live).
__device__ inline void ldsbar() {
  asm volatile("s_waitcnt lgkmcnt(0)" ::: "memory");
  __builtin_amdgcn_s_barrier();
}

// XCD-slab tile mapping: blk%8 = XCD (HW round-robin); each XCD owns 200
// spatially-contiguous tiles (an 80-pixel-row band) so halo re-reads and
// the offconv->dconv handoff stay inside one 4MB L2.
__device__ inline void tile_map(int blk, int& b, int& ty0, int& tx0) {
  int t = (blk & 7) * 200 + (blk >> 3);
  b = t / 400;
  int r = t % 400;
  ty0 = (r / 10) * 4;
  tx0 = (r % 10) * 16;
}

// ---------------------------------------------------------------------------
// prep: prepacked MFMA B-fragments in FP16 (K permuted to kappa = tap*8 + ch
// within each 8-ch chunk, 96-padded; taps 9..11 zero) + zero BN partials.
// ---------------------------------------------------------------------------
__global__ void prep_kernel(const float* __restrict__ cw,
                            const float* __restrict__ ow,
                            unsigned short* __restrict__ Bp,
                            unsigned short* __restrict__ B2p,
                            float* __restrict__ part) {
  int i = blockIdx.x * 256 + threadIdx.x;
  if (i < 32768) part[i] = 0.f;
  if (i < 49152) {                      // dconv weights conv_w[n][c][t], nt 0..3
    int j = i & 7, l = (i >> 3) & 63, rest = i >> 9;
    int ki = rest % 24, nt = rest / 24;
    int kp = ki * 32 + ((l >> 4) << 3) + j;
    int chunk = kp / 96, kq = kp % 96;
    int t = kq >> 3, c = kq & 7;
    int n = nt * 16 + (l & 15);
    float v = (t < 9) ? cw[n * 576 + (chunk * 8 + c) * 9 + t] : 0.f;
    Bp[i] = f16bits(v);
  }
  if (i < 24576) {                      // offconv weights, nt 0..1, n<18
    int j = i & 7, l = (i >> 3) & 63, rest = i >> 9;
    int ki = rest % 24, nt = rest / 24;
    int kp = ki * 32 + ((l >> 4) << 3) + j;
    int chunk = kp / 96, kq = kp % 96;
    int t = kq >> 3, c = kq & 7;
    int n = nt * 16 + (l & 15);
    float v = (t < 9 && n < 18) ? ow[n * 576 + (chunk * 8 + c) * 9 + t] : 0.f;
    B2p[i] = f16bits(v);
  }
}

// ---------------------------------------------------------------------------
// FUSED offconv + dconv, FP16 path, ONE barrier per chunk.
// Round-12 falsified throughput limits (VALU/LDS halved -> dur flat): the
// kernel is barrier-chain-bound (33 barrier-delimited dependency segments,
// ~2.5 blocks/CU residency). This round double-buffers BOTH patch and Af so
// each chunk is {interp->Af[cur] write, patch[nxt] write, ldsbar, prefetch
// chunk+2, MFMA from Af[cur]} -- 18 barriers/block instead of 33, and the
// global prefetch distance grows to 2 chunks (duplicate chunk-7 loads gone).
// Hazards: Af[cur] WAR (read i, rewrite i+2) separated by bar(i+1);
// patch[nxt] write(i)->read(i+1) crosses bar(i); read(i+1)->rewrite(i+2)
// crosses bar(i+1). Inner interp/MFMA identical to round 12.
// LDS = 2*3024 (patch dbuf) + 2*12288 (Af dbuf) + 4608 (offs) = 35232 B
// -> 4 blocks/CU (above measured ~2.5 residency).
// ---------------------------------------------------------------------------
__global__ __launch_bounds__(256, 4) void fused_kernel(
    const float* __restrict__ x, const float* __restrict__ d,
    const f16x8* __restrict__ Bp, const f16x8* __restrict__ B2p,
    float* __restrict__ out, float* __restrict__ off_out,
    float* __restrict__ part) {
  int b, ty0, tx0;
  tile_map(blockIdx.x, b, ty0, tx0);
  const int tid = threadIdx.x;
  const int wv = tid >> 6, lane = tid & 63;
  const int lo = lane >> 4, li = lane & 15;
  const int px = li, py = wv;
  const int h = ty0 + py, w = tx0 + px;

  __shared__ __align__(16) _Float16 patch[2][189 * 8];  // dbuf; ph1: 108 px
  __shared__ f16x8 Af[2][768];                          // dbuf
  __shared__ float offs_s[64 * 18];    // per-pixel 9 taps x (dy,dx)

  const f16x8 zero8 = {(_Float16)0, (_Float16)0, (_Float16)0, (_Float16)0,
                       (_Float16)0, (_Float16)0, (_Float16)0, (_Float16)0};

  // ---- phase-2 x-staging: 189 tasks = one 9x21 pixel each (8ch) ----
  int goff2 = 0, laddr2 = 0;
  bool inr2 = tid < 189, ok2 = false;
  {
    int p = tid;
    int r = p / 21, col = p % 21;
    int gy = ty0 - 2 + r, gx = tx0 - 2 + col;
    ok2 = inr2 && gy >= 0 && gy < HH && gx >= 0 && gx < WW;
    goff2 = ((b * 64) * HH + gy) * WW + gx;
    laddr2 = p * 8;                    // 16B-aligned
  }

  // ================= phase 1: offconv =================
  f32x4 acc0{0.f, 0.f, 0.f, 0.f}, acc1{0.f, 0.f, 0.f, 0.f};
  const int ntA = wv >> 1, mh = wv & 1;
  {
    int poff[3];
    bool tre[3];
#pragma unroll
    for (int kk = 0; kk < 3; ++kk) {
      int t = kk * 4 + lo;
      tre[kk] = (t < 9);
      poff[kk] = tre[kk] ? ((py + t / 3) * 18 + px + t % 3) : 0;
    }

    // phase-1 staging: 108 tasks = one 6x18 pixel each (8ch)
    int goff1 = 0, laddr1 = 0;
    bool inr1 = tid < 108, ok1 = false;
    {
      int p = tid;
      int r = p / 18, col = p % 18;
      int gy = ty0 - 1 + r, gx = tx0 - 1 + col;
      ok1 = inr1 && gy >= 0 && gy < HH && gx >= 0 && gx < WW;
      goff1 = ((b * 64) * HH + gy) * WW + gx;
      laddr1 = p * 8;
    }
    f16x8 g1 = zero8;
    if (ok1) g1 = load8cvt(d + goff1);            // chunk 0
    if (inr1) *(f16x8*)&patch[0][laddr1] = g1;
    ldsbar();                                      // patch[0] ready
    if (ok1) g1 = load8cvt(d + goff1 + CHSTRIDE);  // chunk 1

    for (int chunk = 0; chunk < 8; ++chunk) {
      const int cur = chunk & 1, nxt = cur ^ 1;
      f16x8 bw0 = B2p[((ntA * 24 + chunk * 3 + 0) << 6) + lane];
      f16x8 bw1 = B2p[((ntA * 24 + chunk * 3 + 1) << 6) + lane];
      f16x8 bw2 = B2p[((ntA * 24 + chunk * 3 + 2) << 6) + lane];
#pragma unroll
      for (int kk = 0; kk < 3; ++kk) {
        f16x8 av =
            tre[kk] ? *(const f16x8*)(patch[cur] + poff[kk] * 8) : zero8;
        Af[cur][((wv * 3 + kk) << 6) + lane] = av;
      }
      if (chunk < 7 && inr1) *(f16x8*)&patch[nxt][laddr1] = g1;
      ldsbar();                       // Af[cur] + patch[nxt] ready
      if (chunk < 6 && ok1)
        g1 = load8cvt(d + goff1 + (chunk + 2) * CHSTRIDE);
#pragma unroll
      for (int kk = 0; kk < 3; ++kk) {
        f16x8 bw = (kk == 0) ? bw0 : (kk == 1) ? bw1 : bw2;
        acc0 = __builtin_amdgcn_mfma_f32_16x16x32_f16(
            Af[cur][(((mh * 2) * 3 + kk) << 6) + lane], bw, acc0, 0, 0, 0);
        acc1 = __builtin_amdgcn_mfma_f32_16x16x32_f16(
            Af[cur][(((mh * 2 + 1) * 3 + kk) << 6) + lane], bw, acc1, 0, 0, 0);
      }
    }
  }

  // issue the first x chunk now: HBM latency hides under the phase-1
  // epilogue + phase-boundary barrier
  f16x8 gv = zero8;
  if (ok2) gv = load8cvt(x + goff2);

  {  // phase-1 epilogue: clamp, write global off_out + LDS offs_s
    const int n = ntA * 16 + li;
    if (n < 18) {
#pragma unroll
      for (int f = 0; f < 2; ++f) {
        int mf = mh * 2 + f;
        f32x4 a = f ? acc1 : acc0;
        float* po =
            off_out + ((b * 18 + n) * HH + ty0 + mf) * WW + tx0 + lo * 4;
        float4 v;
        v.x = fminf(1.f, fmaxf(-1.f, a[0]));
        v.y = fminf(1.f, fmaxf(-1.f, a[1]));
        v.z = fminf(1.f, fmaxf(-1.f, a[2]));
        v.w = fminf(1.f, fmaxf(-1.f, a[3]));
        *(float4*)po = v;
        int pix = mf * 16 + lo * 4;
        offs_s[(pix + 0) * 18 + n] = v.x;
        offs_s[(pix + 1) * 18 + n] = v.y;
        offs_s[(pix + 2) * 18 + n] = v.z;
        offs_s[(pix + 3) * 18 + n] = v.w;
      }
    }
  }
  // phase-2 chunk-0 patch write folded before the phase-boundary barrier
  // (phase-1 patch reads all completed before iter-7's ldsbar)
  if (inr2) *(f16x8*)&patch[0][laddr2] = gv;
  ldsbar();                            // offs_s + patch2[0] ready

  // ================= phase 2: dconv =================
  int bs[3];
  float W00[3], W01[3], W10[3], W11[3];
  bool tre[3];
#pragma unroll
  for (int kk = 0; kk < 3; ++kk) {
    int t = kk * 4 + lo;
    tre[kk] = (t < 9);
    if (tre[kk]) {
      float dy = offs_s[(py * 16 + px) * 18 + 2 * t];
      float dx = offs_s[(py * 16 + px) * 18 + 2 * t + 1];
      float pyf = (float)(h - 1 + t / 3) + dy;
      float pxf = (float)(w - 1 + t % 3) + dx;
      float y0 = floorf(pyf), x0 = floorf(pxf);
      float wy = pyf - y0, wx = pxf - x0;
      bs[kk] = ((int)y0 - (ty0 - 2)) * 21 + ((int)x0 - (tx0 - 2));
      W00[kk] = (1.f - wy) * (1.f - wx);
      W01[kk] = (1.f - wy) * wx;
      W10[kk] = wy * (1.f - wx);
      W11[kk] = wy * wx;
    } else {
      bs[kk] = 0;
      W00[kk] = W01[kk] = W10[kk] = W11[kk] = 0.f;
    }
  }

  f32x4 acc[4];
#pragma unroll
  for (int i = 0; i < 4; ++i) acc[i] = f32x4{0.f, 0.f, 0.f, 0.f};
  const int nt = wv;

  if (ok2) gv = load8cvt(x + goff2 + CHSTRIDE);   // chunk 1

  for (int chunk = 0; chunk < 8; ++chunk) {
    const int cur = chunk & 1, nxt = cur ^ 1;
    f16x8 bw0 = Bp[((nt * 24 + chunk * 3 + 0) << 6) + lane];
    f16x8 bw1 = Bp[((nt * 24 + chunk * 3 + 1) << 6) + lane];
    f16x8 bw2 = Bp[((nt * 24 + chunk * 3 + 2) << 6) + lane];
#pragma unroll
    for (int kk = 0; kk < 3; ++kk) {
      f16x8 av;
      if (tre[kk]) {
        const _Float16* q = patch[cur] + bs[kk] * 8;
        f16x8 p00 = *(const f16x8*)(q);            // corner (0,0), 8 ch
        f16x8 p01 = *(const f16x8*)(q + 8);        // corner (0,1)
        f16x8 p10 = *(const f16x8*)(q + 168);      // corner (1,0): +21*8
        f16x8 p11 = *(const f16x8*)(q + 176);      // corner (1,1)
        _Float16 w0 = (_Float16)W00[kk], w1 = (_Float16)W01[kk];
        _Float16 w2 = (_Float16)W10[kk], w3 = (_Float16)W11[kk];
        f16x8 w0v = {w0, w0, w0, w0, w0, w0, w0, w0};
        f16x8 w1v = {w1, w1, w1, w1, w1, w1, w1, w1};
        f16x8 w2v = {w2, w2, w2, w2, w2, w2, w2, w2};
        f16x8 w3v = {w3, w3, w3, w3, w3, w3, w3, w3};
        av = p00 * w0v + p01 * w1v + p10 * w2v + p11 * w3v;
      } else {
        av = zero8;
      }
      Af[cur][((wv * 3 + kk) << 6) + lane] = av;
    }
    if (chunk < 7 && inr2) *(f16x8*)&patch[nxt][laddr2] = gv;
    ldsbar();                         // Af[cur] + patch[nxt] ready
    if (chunk < 6 && ok2)
      gv = load8cvt(x + goff2 + (chunk + 2) * CHSTRIDE);
#pragma unroll
    for (int kk = 0; kk < 3; ++kk) {
      f16x8 bw = (kk == 0) ? bw0 : (kk == 1) ? bw1 : bw2;
#pragma unroll
      for (int mf = 0; mf < 4; ++mf)
        acc[mf] = __builtin_amdgcn_mfma_f32_16x16x32_f16(
            Af[cur][((mf * 3 + kk) << 6) + lane], bw, acc[mf], 0, 0, 0);
    }
  }
  // epilogue: aligned float4 stores + fused BN partial sums
  const int n = nt * 16 + li;
  float s = 0.f, s2 = 0.f;
#pragma unroll
  for (int mf = 0; mf < 4; ++mf) {
    float* po = out + ((b * 64 + n) * HH + ty0 + mf) * WW + tx0 + lo * 4;
    *(float4*)po = make_float4(acc[mf][0], acc[mf][1], acc[mf][2], acc[mf][3]);
#pragma unroll
    for (int r = 0; r < 4; ++r) {
      float v = acc[mf][r];
      s += v;
      s2 = fmaf(v, v, s2);
    }
  }
  // reduce across the 4 lanes (lo=0..3) holding channel n
  s += __shfl_xor(s, 16);  s += __shfl_xor(s, 32);
  s2 += __shfl_xor(s2, 16); s2 += __shfl_xor(s2, 32);
  if (lo == 0) {
    int slot = blockIdx.x & (NSLOT - 1);
    atomicAdd(&part[n * NSLOT + slot], s);
    atomicAdd(&part[(64 + n) * NSLOT + slot], s2);
  }
}

// ---------------------------------------------------------------------------
// reduce BN partials: block j sums part[j][0..255] (f64) -> sums[j]
// ---------------------------------------------------------------------------
__global__ __launch_bounds__(256) void reduce_kernel(
    const float* __restrict__ part, double* __restrict__ sums) {
  const int j = blockIdx.x;
  __shared__ double sh[256];
  sh[threadIdx.x] = (double)part[j * NSLOT + threadIdx.x];
  __syncthreads();
  for (int t = 128; t > 0; t >>= 1) {
    if (threadIdx.x < t) sh[threadIdx.x] += sh[threadIdx.x + t];
    __syncthreads();
  }
  if (threadIdx.x == 0) sums[j] = sh[0];
}

// ---------------------------------------------------------------------------
// BN apply + ReLU, in place on d_out's conv region (float4 vectorized).
// ---------------------------------------------------------------------------
__global__ __launch_bounds__(256) void bnapply_kernel(
    float* __restrict__ out, const double* __restrict__ sums,
    const float* __restrict__ gamma, const float* __restrict__ beta) {
  const int i = blockIdx.x * 256 + threadIdx.x;
  if (i >= OUT_ELEMS / 4) return;
  const int o = (i / (HWD / 4)) & 63;
  const float n_inv = 1.0f / (float)(BB * HWD);
  float mean = (float)sums[o] * n_inv;
  float var = (float)sums[64 + o] * n_inv - mean * mean;
  float inv = gamma[o] * rsqrtf(var + EPSBN);
  float bt = beta[o];
  float4 v = ((float4*)out)[i];
  v.x = fmaxf(0.f, (v.x - mean) * inv + bt);
  v.y = fmaxf(0.f, (v.y - mean) * inv + bt);
  v.z = fmaxf(0.f, (v.z - mean) * inv + bt);
  v.w = fmaxf(0.f, (v.w - mean) * inv + bt);
  ((float4*)out)[i] = v;
}

extern "C" void kernel_launch(void* const* d_in, const int* in_sizes, int n_in,
                              void* d_out, int out_size, void* d_ws, size_t ws_size,
                              hipStream_t stream) {
  const float* x = (const float*)d_in[0];
  const float* d = (const float*)d_in[1];
  const float* ow = (const float*)d_in[2];
  const float* cw = (const float*)d_in[3];
  const float* gamma = (const float*)d_in[4];
  const float* beta = (const float*)d_in[5];

  float* out = (float*)d_out;
  float* off_out = out + OUT_ELEMS;

  // ws: sums double[128] | Bp ush[49152] | B2p ush[24576] | part f32[32768]
  double* sums = (double*)d_ws;
  unsigned short* Bp = (unsigned short*)((char*)d_ws + 1024);
  unsigned short* B2p = Bp + 49152;
  float* part = (float*)(B2p + 24576);

  prep_kernel<<<192, 256, 0, stream>>>(cw, ow, Bp, B2p, part);

  fused_kernel<<<1600, 256, 0, stream>>>(x, d, (const f16x8*)Bp,
                                         (const f16x8*)B2p, out, off_out,
                                         part);

  reduce_kernel<<<128, 256, 0, stream>>>(part, sums);
  bnapply_kernel<<<(OUT_ELEMS / 4 + 255) / 256, 256, 0, stream>>>(
      out, sums, gamma, beta);
}